// Round 12
// baseline (292.725 us; speedup 1.0000x reference)
//
#include <hip/hip_runtime.h>
#include <hip/hip_bf16.h>
#include <math.h>

typedef __hip_bfloat16 bf16;
typedef short short8 __attribute__((ext_vector_type(8)));
typedef float floatx4 __attribute__((ext_vector_type(4)));

#define B_    8
#define T_    32
#define N_    64
#define F_    6
#define D_    128
#define E_    4032      // N*(N-1)
#define BT_   256       // B*T
#define BN_   512       // B*N

__device__ __forceinline__ float gelu_exact(float x) {
    return 0.5f * x * (1.0f + erff(x * 0.70710678118654752f));
}
__device__ __forceinline__ float bfbits2f(short s) {
    unsigned int u = ((unsigned int)(unsigned short)s) << 16;
    return __uint_as_float(u);
}
// load 32 consecutive bf16 from LDS (16B-aligned) as fp32
__device__ __forceinline__ void ld32lds(const bf16* p, float* o) {
    const short8* sp = (const short8*)p;
#pragma unroll
    for (int i = 0; i < 4; i++) {
        short8 s = sp[i];
#pragma unroll
        for (int j = 0; j < 8; j++) o[i * 8 + j] = bfbits2f(s[j]);
    }
}

// ---------------------------------------------------------------------------
// Repack weights into MFMA B-fragment layout + pack spatial qkv biases.
struct RepackDesc { const float* W; bf16* out; int K, N, ntt, ntoff, L, start; };
struct RepackArgs {
    RepackDesc d[9]; int total;
    const float *bq, *bk, *bv; float* spb;
};

__global__ void k_repack(RepackArgs ra) {
    int gid = blockIdx.x * blockDim.x + threadIdx.x;
    if (gid >= ra.total) {
        int i = gid - ra.total;
        if (i < 3 * 384) {
            int l = i / 384, c = i % 384;
            float v = (c < 128) ? ra.bq[l * 128 + c]
                    : (c < 256) ? ra.bk[l * 128 + c - 128]
                                : ra.bv[l * 128 + c - 256];
            ra.spb[i] = v;
        }
        return;
    }
    int fi = 0;
    while (fi < 8 && gid >= ra.d[fi + 1].start) fi++;
    RepackDesc dd = ra.d[fi];
    int r = gid - dd.start;
    int lane = r & 63; r >>= 6;
    int ntiles = dd.N >> 4;
    int nt = r % ntiles; r /= ntiles;
    int ktiles = dd.K >> 5;
    int kt = r % ktiles;
    int l = r / ktiles;
    int quad = lane >> 4, cc = lane & 15;
    const float* Wl = dd.W + (size_t)l * dd.K * dd.N;
    bf16* o = dd.out + ((((size_t)l * ktiles + kt) * dd.ntt + nt + dd.ntoff) * 64 + lane) * 8;
    int kb = kt * 32 + quad * 8;
    int n = nt * 16 + cc;
#pragma unroll
    for (int j = 0; j < 8; j++)
        o[j] = __float2bfloat16(Wl[(size_t)(kb + j) * dd.N + n]);
}

// ---------------------------------------------------------------------------
// FUSED 3-layer spatial stack (round-8/11 proven version). One block per (b,t)
// graph, 512 thr = 8 waves. Padded strides, EAs in LDS, P hi/lo split PV.
__global__ __launch_bounds__(512, 1)
void k_spatial3(const float* __restrict__ inp, const float* __restrict__ projW,
                const float* __restrict__ projB,
                const short8* __restrict__ BpQKV, const short8* __restrict__ BpWS,
                const float* __restrict__ spb, const float* __restrict__ bs,
                const float* __restrict__ lng, const float* __restrict__ lnb,
                const float* __restrict__ ea, const float* __restrict__ Weg,
                const float* __restrict__ beg, const float* __restrict__ tpos,
                float* __restrict__ z32g) {
    __shared__ short smem[61312];            // 122624 B
    bf16* hb = (bf16*)smem;                  // [0,8704)s: 64 x 136
    bf16* qk = (bf16*)(smem + 8704);         // 64 x 264 (q|k)
    float* aggf = (float*)(smem + 8704);     // overlay qk: 64 x 128 fp32
    float* fsm = (float*)(smem + 8704);      // overlay qk: proj staging
    bf16* Vt = (bf16*)(smem + 25600);        // 128 x 72 (d-major)
    bf16* Ps = (bf16*)(smem + 34816);        // h*4608 + m*72
    float* EAs = (float*)(smem + 53248);     // 4032 fp32

    int bt = blockIdx.x;
    int tid = threadIdx.x;
    int lane = tid & 63, w = tid >> 6;
    int quad = lane >> 4, col = lane & 15;
    int w4 = w & 3, wh = w >> 2;
    const float scale = 0.17677669529663687f;   // 1/sqrt(32)

    for (int i = tid; i < 896; i += 512)
        fsm[i] = (i < 768) ? projW[i] : projB[i - 768];
    {
        const float* eag = ea + (size_t)bt * E_;
        for (int i = tid; i < E_; i += 512) EAs[i] = eag[i];
    }
    __syncthreads();
    float hreg[32];
    if (w < 4) {
#pragma unroll
        for (int r = 0; r < 4; r++) {
            int n = w * 16 + quad * 4 + r;
            const float* xr = inp + (size_t)(bt * 64 + n) * F_;
            float xin[6];
#pragma unroll
            for (int k2 = 0; k2 < 6; k2++) xin[k2] = xr[k2];
#pragma unroll
            for (int tt = 0; tt < 8; tt++) {
                int c = tt * 16 + col;
                float a = fsm[768 + c];
#pragma unroll
                for (int k2 = 0; k2 < 6; k2++) a = fmaf(xin[k2], fsm[k2 * 128 + c], a);
                hreg[tt * 4 + r] = a;
                hb[n * 136 + c] = __float2bfloat16(a);
            }
        }
    }
    __syncthreads();                         // B0

    for (int l = 0; l < 3; l++) {
        // ---- phase 1: qkv GEMM ----
        {
            floatx4 acc[12];
#pragma unroll
            for (int tt = 0; tt < 12; tt++) acc[tt] = (floatx4){0.f, 0.f, 0.f, 0.f};
            const short8* bpl = BpQKV + (size_t)l * 6144;
            for (int kt = 0; kt < 4; kt++) {
                short8 a = *(const short8*)&hb[(w4 * 16 + col) * 136 + kt * 32 + quad * 8];
                const short8* bp = bpl + (size_t)(kt * 24 + wh * 12) * 64 + lane;
#pragma unroll
                for (int tt = 0; tt < 12; tt++)
                    acc[tt] = __builtin_amdgcn_mfma_f32_16x16x32_bf16(a, bp[tt * 64], acc[tt], 0, 0, 0);
            }
            const float* bias = spb + l * 384;
#pragma unroll
            for (int tt = 0; tt < 12; tt++) {
                int c = wh * 192 + tt * 16 + col;
                float bv = bias[c];
#pragma unroll
                for (int r = 0; r < 4; r++) {
                    int row = w4 * 16 + quad * 4 + r;
                    bf16 v = __float2bfloat16(acc[tt][r] + bv);
                    if (c < 256) qk[row * 264 + c] = v;
                    else         Vt[(c - 256) * 72 + row] = v;
                }
            }
        }
        __syncthreads();                     // B1
        // ---- phase 2: attention. wave=(h=w4, rowhalf=wh) ----
        int h = w4, half = wh;
        int hoff = h * 32;
        const float* Wel = Weg + l * 128 + hoff;
        const float* bel = beg + l * 128 + hoff;
        float qWe;
        {
            int dst = half * 32 + (lane & 31);
            float qr[32];
            ld32lds(&qk[dst * 264 + hoff], qr);
            float s0 = 0.f, s1 = 0.f, s2 = 0.f, s3 = 0.f;
#pragma unroll
            for (int c2 = 0; c2 < 32; c2 += 4) {
                s0 = fmaf(qr[c2], Wel[c2], s0);
                s1 = fmaf(qr[c2 + 1], Wel[c2 + 1], s1);
                s2 = fmaf(qr[c2 + 2], Wel[c2 + 2], s2);
                s3 = fmaf(qr[c2 + 3], Wel[c2 + 3], s3);
            }
            qWe = (s0 + s1) + (s2 + s3);
        }
        float s[2][4][4], ev[2][4][4];
        {
            short8 aA[2], bB[4];
#pragma unroll
            for (int mtl = 0; mtl < 2; mtl++)
                aA[mtl] = *(const short8*)&qk[((half * 2 + mtl) * 16 + col) * 264 + hoff + quad * 8];
#pragma unroll
            for (int nt = 0; nt < 4; nt++)
                bB[nt] = *(const short8*)&qk[(nt * 16 + col) * 264 + 128 + hoff + quad * 8];
#pragma unroll
            for (int mtl = 0; mtl < 2; mtl++)
#pragma unroll
                for (int nt = 0; nt < 4; nt++) {
                    floatx4 acc = (floatx4){0.f, 0.f, 0.f, 0.f};
                    acc = __builtin_amdgcn_mfma_f32_16x16x32_bf16(aA[mtl], bB[nt], acc, 0, 0, 0);
#pragma unroll
                    for (int r = 0; r < 4; r++) s[mtl][nt][r] = acc[r];
                }
        }
        __syncthreads();                     // B2: all qk reads done
        float ls[2][4], ae[2][4], inv[2][4];
#pragma unroll
        for (int mtl = 0; mtl < 2; mtl++)
#pragma unroll
            for (int r = 0; r < 4; r++) {
                int m = half * 32 + mtl * 16 + quad * 4 + r;
                float qWeR = __shfl(qWe, mtl * 16 + quad * 4 + r, 64);
                float rmax = -1e30f;
#pragma unroll
                for (int nt = 0; nt < 4; nt++) {
                    int n = nt * 16 + col;
                    bool diag = (m == n);
                    int eid = diag ? 0 : (n * 63 + m - (m > n ? 1 : 0));
                    float eav = diag ? 0.f : EAs[eid];
                    ev[mtl][nt][r] = eav;
                    float al = diag ? -1e30f
                                    : scale * (s[mtl][nt][r] + eav * qWeR);
                    s[mtl][nt][r] = al;
                    rmax = fmaxf(rmax, al);
                }
#pragma unroll
                for (int mk2 = 1; mk2 <= 8; mk2 <<= 1)
                    rmax = fmaxf(rmax, __shfl_xor(rmax, mk2, 64));
                float lsum = 0.f, aesum = 0.f;
#pragma unroll
                for (int nt = 0; nt < 4; nt++) {
                    float p = __expf(s[mtl][nt][r] - rmax);
                    s[mtl][nt][r] = p;
                    lsum += p;
                    aesum = fmaf(p, ev[mtl][nt][r], aesum);
                }
#pragma unroll
                for (int mk2 = 1; mk2 <= 8; mk2 <<= 1) {
                    lsum += __shfl_xor(lsum, mk2, 64);
                    aesum += __shfl_xor(aesum, mk2, 64);
                }
                ls[mtl][r] = lsum;
                ae[mtl][r] = aesum;
                inv[mtl][r] = 1.0f / lsum;
            }
        // PV: P hi/lo compensated bf16 split (Ps wave-private)
        bf16* PsH = Ps + h * 4608;
        floatx4 oacc[2][2];
#pragma unroll
        for (int mtl = 0; mtl < 2; mtl++)
#pragma unroll
            for (int ntB = 0; ntB < 2; ntB++) oacc[mtl][ntB] = (floatx4){0.f, 0.f, 0.f, 0.f};
#pragma unroll
        for (int p = 0; p < 2; p++) {
#pragma unroll
            for (int mtl = 0; mtl < 2; mtl++)
#pragma unroll
                for (int q2 = 0; q2 < 2; q2++) {
                    int nl = q2 * 16 + col;
                    int base0 = (half * 32 + mtl * 16 + quad * 4) * 72 + ((nl >> 3) * 2) * 8 + (nl & 7);
#pragma unroll
                    for (int r = 0; r < 4; r++) {
                        float p_ = s[mtl][2 * p + q2][r];
                        bf16 hi = __float2bfloat16(p_);
                        bf16 lo = __float2bfloat16(p_ - bfbits2f(*(short*)&hi));
                        PsH[base0 + r * 72] = hi;
                        PsH[base0 + r * 72 + 8] = lo;
                    }
                }
            short8 aPh[2], aPl[2], bV[2];
#pragma unroll
            for (int mtl = 0; mtl < 2; mtl++) {
                int rb = (half * 32 + mtl * 16 + col) * 72 + quad * 16;
                aPh[mtl] = *(const short8*)&PsH[rb];
                aPl[mtl] = *(const short8*)&PsH[rb + 8];
            }
#pragma unroll
            for (int ntB = 0; ntB < 2; ntB++)
                bV[ntB] = *(const short8*)&Vt[(hoff + ntB * 16 + col) * 72 + p * 32 + quad * 8];
#pragma unroll
            for (int mtl = 0; mtl < 2; mtl++)
#pragma unroll
                for (int ntB = 0; ntB < 2; ntB++) {
                    oacc[mtl][ntB] = __builtin_amdgcn_mfma_f32_16x16x32_bf16(aPh[mtl], bV[ntB], oacc[mtl][ntB], 0, 0, 0);
                    oacc[mtl][ntB] = __builtin_amdgcn_mfma_f32_16x16x32_bf16(aPl[mtl], bV[ntB], oacc[mtl][ntB], 0, 0, 0);
                }
        }
#pragma unroll
        for (int mtl = 0; mtl < 2; mtl++)
#pragma unroll
            for (int ntB = 0; ntB < 2; ntB++) {
                int c = hoff + ntB * 16 + col;
                float Wc = Wel[ntB * 16 + col];
                float bc = bel[ntB * 16 + col];
#pragma unroll
                for (int r = 0; r < 4; r++) {
                    int m = half * 32 + mtl * 16 + quad * 4 + r;
                    aggf[m * 128 + c] = fmaf(fmaf(ae[mtl][r], Wc, oacc[mtl][ntB][r]),
                                             inv[mtl][r], bc);
                }
            }
        __syncthreads();                     // B3: agg visible
        // ---- epilogue: Ws GEMM + agg + residual + LN (waves 0-3) ----
        if (w < 4) {
            floatx4 acc2[8];
#pragma unroll
            for (int tt = 0; tt < 8; tt++) acc2[tt] = (floatx4){0.f, 0.f, 0.f, 0.f};
            const short8* bpl = BpWS + (size_t)l * 2048;
            for (int kt = 0; kt < 4; kt++) {
                short8 a = *(const short8*)&hb[(w * 16 + col) * 136 + kt * 32 + quad * 8];
                const short8* bp = bpl + (size_t)(kt * 8) * 64 + lane;
#pragma unroll
                for (int tt = 0; tt < 8; tt++)
                    acc2[tt] = __builtin_amdgcn_mfma_f32_16x16x32_bf16(a, bp[tt * 64], acc2[tt], 0, 0, 0);
            }
            const float* bsl = bs + l * 128;
            float vv[32], rs[4] = {0.f, 0.f, 0.f, 0.f};
#pragma unroll
            for (int tt = 0; tt < 8; tt++) {
                int c = tt * 16 + col;
                float bv = bsl[c];
#pragma unroll
                for (int r = 0; r < 4; r++) {
                    int row = w * 16 + quad * 4 + r;
                    float v = acc2[tt][r] + bv + aggf[row * 128 + c] + hreg[tt * 4 + r];
                    vv[tt * 4 + r] = v;
                    rs[r] += v;
                }
            }
#pragma unroll
            for (int m = 1; m <= 8; m <<= 1)
#pragma unroll
                for (int r = 0; r < 4; r++) rs[r] += __shfl_xor(rs[r], m, 64);
            float mean[4], vs[4] = {0.f, 0.f, 0.f, 0.f};
#pragma unroll
            for (int r = 0; r < 4; r++) mean[r] = rs[r] * (1.0f / 128.0f);
#pragma unroll
            for (int i = 0; i < 32; i++) {
                float d = vv[i] - mean[i & 3];
                vv[i] = d;
                vs[i & 3] += d * d;
            }
#pragma unroll
            for (int m = 1; m <= 8; m <<= 1)
#pragma unroll
                for (int r = 0; r < 4; r++) vs[r] += __shfl_xor(vs[r], m, 64);
            float inv2[4];
#pragma unroll
            for (int r = 0; r < 4; r++) inv2[r] = rsqrtf(vs[r] * (1.0f / 128.0f) + 1e-5f);
            const float* gl = lng + l * 128;
            const float* bl = lnb + l * 128;
            if (l < 2) {
#pragma unroll
                for (int tt = 0; tt < 8; tt++) {
                    int c = tt * 16 + col;
                    float gc = gl[c], bc = bl[c];
#pragma unroll
                    for (int r = 0; r < 4; r++) {
                        float y = vv[tt * 4 + r] * inv2[r] * gc + bc;
                        int n = w * 16 + quad * 4 + r;
                        hreg[tt * 4 + r] = y;
                        hb[n * 136 + c] = __float2bfloat16(y);
                    }
                }
            } else {
                int b = bt >> 5, t_ = bt & 31;
#pragma unroll
                for (int tt = 0; tt < 8; tt++) {
                    int c = tt * 16 + col;
                    float gc = gl[c], bc = bl[c], pc = tpos[t_ * 128 + c];
#pragma unroll
                    for (int r = 0; r < 4; r++) {
                        float y = vv[tt * 4 + r] * inv2[r] * gc + bc;
                        int n = w * 16 + quad * 4 + r;
                        z32g[((size_t)(b * 64 + n) * 32 + t_) * 128 + c] = y + pc;
                    }
                }
            }
        }
        __syncthreads();                     // B4
    }
}

// ---------------------------------------------------------------------------
// FUSED 3-layer temporal stack, 2 SEQUENCES PER BLOCK. 256 blocks x 512 thr
// = 8 waves; GEMM wave = (seq=w&1, col-band cq=w>>1) covering 32 rows
// (2 m-tiles) — every B-fragment feeds 2 MFMAs (halves L2->VGPR traffic);
// attention wave = (seq, head=cq). LDS 128000 B -> 1 block/CU;
// launch_bounds(512,2) -> 256-VGPR cap (no spills).
__global__ __launch_bounds__(512, 2)
void k_temporal3(const float* __restrict__ z32g,
                 const short8* __restrict__ BpQKV, const short8* __restrict__ BpWO,
                 const short8* __restrict__ BpW1, const short8* __restrict__ BpW2,
                 const float* __restrict__ bqkv, const float* __restrict__ bo,
                 const float* __restrict__ ln1g, const float* __restrict__ ln1b,
                 const float* __restrict__ b1, const float* __restrict__ b2,
                 const float* __restrict__ ln2g, const float* __restrict__ ln2b,
                 bf16* __restrict__ zlastb) {
    __shared__ short smem[64000];            // 128000 B
    bf16* zb  = (bf16*)smem;                 // [s*4352 + row*136 + c]
    bf16* qk  = (bf16*)(smem + 8704);        // [s*8448 + row*264 + c]
    bf16* Ps  = (bf16*)(smem + 25600);       // [w*2304 + row*72 + ...]
    bf16* Vt  = (bf16*)(smem + 44032);       // [s*5120 + d*40 + t]
    bf16* o16 = (bf16*)(smem + 54272);       // [s*4352 + row*136 + c]
    float* lnp = (float*)(smem + 62976);     // [((s*4+cq)*32+row)*2 +{0,1}]
    bf16* f1  = (bf16*)(smem + 8704);        // overlay qk+Ps: [s*16640+row*520+c]

    int bn0 = blockIdx.x * 2;
    int tid = threadIdx.x;
    int lane = tid & 63, w = tid >> 6;
    int quad = lane >> 4, col = lane & 15;
    int sq = w & 1, cq = w >> 1;
    const float scale = 0.17677669529663687f;

    // ---- stage z for both sequences ----
    for (int i = tid; i < 8192; i += 512) {
        int s = i >> 12, j = i & 4095;
        float v = z32g[(size_t)(bn0 + s) * 4096 + j];
        zb[s * 4352 + (j >> 7) * 136 + (j & 127)] = __float2bfloat16(v);
    }
    float zreg[16];
#pragma unroll
    for (int mt = 0; mt < 2; mt++)
#pragma unroll
        for (int t2 = 0; t2 < 2; t2++)
#pragma unroll
            for (int r = 0; r < 4; r++)
                zreg[mt * 8 + t2 * 4 + r] =
                    z32g[(size_t)(bn0 + sq) * 4096 +
                         (mt * 16 + quad * 4 + r) * 128 + cq * 32 + t2 * 16 + col];
    __syncthreads();

    for (int l = 0; l < 3; l++) {
        // ---- qkv GEMM: wave (sq,cq): 2 m-tiles x 6 col-tiles (96-col band) ----
        {
            floatx4 acc[2][6];
#pragma unroll
            for (int mt = 0; mt < 2; mt++)
#pragma unroll
                for (int tt = 0; tt < 6; tt++) acc[mt][tt] = (floatx4){0.f, 0.f, 0.f, 0.f};
            const short8* bpl = BpQKV + (size_t)l * 6144;
            for (int kt = 0; kt < 4; kt++) {
                short8 a0 = *(const short8*)&zb[sq * 4352 + col * 136 + kt * 32 + quad * 8];
                short8 a1 = *(const short8*)&zb[sq * 4352 + (16 + col) * 136 + kt * 32 + quad * 8];
                const short8* bp = bpl + (size_t)(kt * 24 + cq * 6) * 64 + lane;
#pragma unroll
                for (int tt = 0; tt < 6; tt++) {
                    short8 b = bp[tt * 64];
                    acc[0][tt] = __builtin_amdgcn_mfma_f32_16x16x32_bf16(a0, b, acc[0][tt], 0, 0, 0);
                    acc[1][tt] = __builtin_amdgcn_mfma_f32_16x16x32_bf16(a1, b, acc[1][tt], 0, 0, 0);
                }
            }
            const float* bias = bqkv + l * 384;
#pragma unroll
            for (int tt = 0; tt < 6; tt++) {
                int c = cq * 96 + tt * 16 + col;
                float bv = bias[c];
#pragma unroll
                for (int mt = 0; mt < 2; mt++)
#pragma unroll
                    for (int r = 0; r < 4; r++) {
                        int row = mt * 16 + quad * 4 + r;
                        bf16 v = __float2bfloat16(acc[mt][tt][r] + bv);
                        if (c < 256) qk[sq * 8448 + row * 264 + c] = v;
                        else         Vt[sq * 5120 + (c - 256) * 40 + row] = v;
                    }
            }
        }
        __syncthreads();                     // B1
        // ---- attention: wave (sq, head=cq), 2 m-tiles x 2 n-tiles ----
        {
            int hoff = cq * 32;
            bf16* PsH = Ps + w * 2304;
            const bf16* qkS = qk + sq * 8448;
            float s[2][2][4];
            short8 aA[2], bB[2];
#pragma unroll
            for (int mt = 0; mt < 2; mt++)
                aA[mt] = *(const short8*)&qkS[(mt * 16 + col) * 264 + hoff + quad * 8];
#pragma unroll
            for (int nt = 0; nt < 2; nt++)
                bB[nt] = *(const short8*)&qkS[(nt * 16 + col) * 264 + 128 + hoff + quad * 8];
#pragma unroll
            for (int mt = 0; mt < 2; mt++)
#pragma unroll
                for (int nt = 0; nt < 2; nt++) {
                    floatx4 acc = (floatx4){0.f, 0.f, 0.f, 0.f};
                    acc = __builtin_amdgcn_mfma_f32_16x16x32_bf16(aA[mt], bB[nt], acc, 0, 0, 0);
#pragma unroll
                    for (int r = 0; r < 4; r++) s[mt][nt][r] = acc[r];
                }
            float inv[2][4];
#pragma unroll
            for (int mt = 0; mt < 2; mt++)
#pragma unroll
                for (int r = 0; r < 4; r++) {
                    int m = mt * 16 + quad * 4 + r;
                    float rmax = -1e30f;
#pragma unroll
                    for (int nt = 0; nt < 2; nt++) {
                        int n = nt * 16 + col;
                        float al = (n > m) ? -1e30f : s[mt][nt][r] * scale;
                        s[mt][nt][r] = al;
                        rmax = fmaxf(rmax, al);
                    }
#pragma unroll
                    for (int mk2 = 1; mk2 <= 8; mk2 <<= 1)
                        rmax = fmaxf(rmax, __shfl_xor(rmax, mk2, 64));
                    float lsum = 0.f;
#pragma unroll
                    for (int nt = 0; nt < 2; nt++) {
                        float p = __expf(s[mt][nt][r] - rmax);
                        s[mt][nt][r] = p;
                        lsum += p;
                    }
#pragma unroll
                    for (int mk2 = 1; mk2 <= 8; mk2 <<= 1)
                        lsum += __shfl_xor(lsum, mk2, 64);
                    inv[mt][r] = 1.0f / lsum;
                }
            // P hi/lo stores (wave-private region)
#pragma unroll
            for (int mt = 0; mt < 2; mt++)
#pragma unroll
                for (int nt = 0; nt < 2; nt++) {
                    int n = nt * 16 + col;
                    int base0 = (mt * 16 + quad * 4) * 72 + ((n >> 3) * 2) * 8 + (n & 7);
#pragma unroll
                    for (int r = 0; r < 4; r++) {
                        float p_ = s[mt][nt][r];
                        bf16 hi = __float2bfloat16(p_);
                        bf16 lo = __float2bfloat16(p_ - bfbits2f(*(short*)&hi));
                        PsH[base0 + r * 72] = hi;
                        PsH[base0 + r * 72 + 8] = lo;
                    }
                }
            // PV (hi + lo)
            floatx4 oacc[2][2];
#pragma unroll
            for (int mt = 0; mt < 2; mt++)
#pragma unroll
                for (int nt = 0; nt < 2; nt++) oacc[mt][nt] = (floatx4){0.f, 0.f, 0.f, 0.f};
            short8 aPh[2], aPl[2], bV[2];
#pragma unroll
            for (int mt = 0; mt < 2; mt++) {
                int rb = (mt * 16 + col) * 72 + quad * 16;
                aPh[mt] = *(const short8*)&PsH[rb];
                aPl[mt] = *(const short8*)&PsH[rb + 8];
            }
#pragma unroll
            for (int nt = 0; nt < 2; nt++)
                bV[nt] = *(const short8*)&Vt[sq * 5120 + (hoff + nt * 16 + col) * 40 + quad * 8];
#pragma unroll
            for (int mt = 0; mt < 2; mt++)
#pragma unroll
                for (int nt = 0; nt < 2; nt++) {
                    oacc[mt][nt] = __builtin_amdgcn_mfma_f32_16x16x32_bf16(aPh[mt], bV[nt], oacc[mt][nt], 0, 0, 0);
                    oacc[mt][nt] = __builtin_amdgcn_mfma_f32_16x16x32_bf16(aPl[mt], bV[nt], oacc[mt][nt], 0, 0, 0);
                }
#pragma unroll
            for (int mt = 0; mt < 2; mt++)
#pragma unroll
                for (int nt = 0; nt < 2; nt++) {
                    int c = hoff + nt * 16 + col;
#pragma unroll
                    for (int r = 0; r < 4; r++)
                        o16[sq * 4352 + (mt * 16 + quad * 4 + r) * 136 + c] =
                            __float2bfloat16(oacc[mt][nt][r] * inv[mt][r]);
                }
        }
        __syncthreads();                     // B2
        // ---- Wo GEMM + residual + LN1: wave (sq,cq), 2 mt x 2 tiles ----
        {
            floatx4 acc2[2][2];
#pragma unroll
            for (int mt = 0; mt < 2; mt++)
#pragma unroll
                for (int tt = 0; tt < 2; tt++) acc2[mt][tt] = (floatx4){0.f, 0.f, 0.f, 0.f};
            const short8* bpl = BpWO + (size_t)l * 2048;
            for (int kt = 0; kt < 4; kt++) {
                short8 a0 = *(const short8*)&o16[sq * 4352 + col * 136 + kt * 32 + quad * 8];
                short8 a1 = *(const short8*)&o16[sq * 4352 + (16 + col) * 136 + kt * 32 + quad * 8];
                const short8* bp = bpl + (size_t)(kt * 8 + cq * 2) * 64 + lane;
#pragma unroll
                for (int tt = 0; tt < 2; tt++) {
                    short8 b = bp[tt * 64];
                    acc2[0][tt] = __builtin_amdgcn_mfma_f32_16x16x32_bf16(a0, b, acc2[0][tt], 0, 0, 0);
                    acc2[1][tt] = __builtin_amdgcn_mfma_f32_16x16x32_bf16(a1, b, acc2[1][tt], 0, 0, 0);
                }
            }
            const float* bol = bo + l * 128;
            float vv[16], rs[2][4], rq[2][4];
#pragma unroll
            for (int mt = 0; mt < 2; mt++)
#pragma unroll
                for (int r = 0; r < 4; r++) { rs[mt][r] = 0.f; rq[mt][r] = 0.f; }
#pragma unroll
            for (int mt = 0; mt < 2; mt++)
#pragma unroll
                for (int tt = 0; tt < 2; tt++) {
                    int c = cq * 32 + tt * 16 + col;
                    float bv = bol[c];
#pragma unroll
                    for (int r = 0; r < 4; r++) {
                        float v = acc2[mt][tt][r] + bv + zreg[mt * 8 + tt * 4 + r];
                        vv[mt * 8 + tt * 4 + r] = v;
                        rs[mt][r] += v;
                        rq[mt][r] = fmaf(v, v, rq[mt][r]);
                    }
                }
#pragma unroll
            for (int m = 1; m <= 8; m <<= 1)
#pragma unroll
                for (int mt = 0; mt < 2; mt++)
#pragma unroll
                    for (int r = 0; r < 4; r++) {
                        rs[mt][r] += __shfl_xor(rs[mt][r], m, 64);
                        rq[mt][r] += __shfl_xor(rq[mt][r], m, 64);
                    }
            if (col == 0) {
#pragma unroll
                for (int mt = 0; mt < 2; mt++)
#pragma unroll
                    for (int r = 0; r < 4; r++) {
                        int row = mt * 16 + quad * 4 + r;
                        lnp[((sq * 4 + cq) * 32 + row) * 2] = rs[mt][r];
                        lnp[((sq * 4 + cq) * 32 + row) * 2 + 1] = rq[mt][r];
                    }
            }
            __syncthreads();                 // B3
            const float* gl = ln1g + l * 128;
            const float* bl = ln1b + l * 128;
#pragma unroll
            for (int mt = 0; mt < 2; mt++)
#pragma unroll
                for (int r = 0; r < 4; r++) {
                    int row = mt * 16 + quad * 4 + r;
                    float sm = 0.f, sqs = 0.f;
#pragma unroll
                    for (int q2 = 0; q2 < 4; q2++) {
                        sm += lnp[((sq * 4 + q2) * 32 + row) * 2];
                        sqs += lnp[((sq * 4 + q2) * 32 + row) * 2 + 1];
                    }
                    float mean = sm * (1.0f / 128.0f);
                    float var = sqs * (1.0f / 128.0f) - mean * mean;
                    float iv = rsqrtf(var + 1e-5f);
#pragma unroll
                    for (int tt = 0; tt < 2; tt++) {
                        int c = cq * 32 + tt * 16 + col;
                        float y = (vv[mt * 8 + tt * 4 + r] - mean) * iv * gl[c] + bl[c];
                        zreg[mt * 8 + tt * 4 + r] = y;
                        zb[sq * 4352 + row * 136 + c] = __float2bfloat16(y);
                    }
                }
        }
        __syncthreads();                     // B4
        // ---- W1 GEMM + gelu: wave (sq,cq): 2 mt x 8 tiles (128-col band) ----
        {
            floatx4 acc3[2][8];
#pragma unroll
            for (int mt = 0; mt < 2; mt++)
#pragma unroll
                for (int tt = 0; tt < 8; tt++) acc3[mt][tt] = (floatx4){0.f, 0.f, 0.f, 0.f};
            const short8* bpl = BpW1 + (size_t)l * 8192;
            for (int kt = 0; kt < 4; kt++) {
                short8 a0 = *(const short8*)&zb[sq * 4352 + col * 136 + kt * 32 + quad * 8];
                short8 a1 = *(const short8*)&zb[sq * 4352 + (16 + col) * 136 + kt * 32 + quad * 8];
                const short8* bp = bpl + (size_t)(kt * 32 + cq * 8) * 64 + lane;
#pragma unroll
                for (int tt = 0; tt < 8; tt++) {
                    short8 b = bp[tt * 64];
                    acc3[0][tt] = __builtin_amdgcn_mfma_f32_16x16x32_bf16(a0, b, acc3[0][tt], 0, 0, 0);
                    acc3[1][tt] = __builtin_amdgcn_mfma_f32_16x16x32_bf16(a1, b, acc3[1][tt], 0, 0, 0);
                }
            }
            const float* b1l = b1 + l * 512;
#pragma unroll
            for (int tt = 0; tt < 8; tt++) {
                int c = cq * 128 + tt * 16 + col;
                float bv = b1l[c];
#pragma unroll
                for (int mt = 0; mt < 2; mt++)
#pragma unroll
                    for (int r = 0; r < 4; r++) {
                        float v = gelu_exact(acc3[mt][tt][r] + bv);
                        f1[sq * 16640 + (mt * 16 + quad * 4 + r) * 520 + c] = __float2bfloat16(v);
                    }
            }
        }
        __syncthreads();                     // B5
        // ---- W2 GEMM + residual + LN2: wave (sq,cq), 2 mt x 2 tiles, K=512 ----
        {
            floatx4 acc4[2][2];
#pragma unroll
            for (int mt = 0; mt < 2; mt++)
#pragma unroll
                for (int tt = 0; tt < 2; tt++) acc4[mt][tt] = (floatx4){0.f, 0.f, 0.f, 0.f};
            const short8* bpl = BpW2 + (size_t)l * 8192;
            for (int kt = 0; kt < 16; kt++) {
                short8 a0 = *(const short8*)&f1[sq * 16640 + col * 520 + kt * 32 + quad * 8];
                short8 a1 = *(const short8*)&f1[sq * 16640 + (16 + col) * 520 + kt * 32 + quad * 8];
                const short8* bp = bpl + (size_t)(kt * 8 + cq * 2) * 64 + lane;
#pragma unroll
                for (int tt = 0; tt < 2; tt++) {
                    short8 b = bp[tt * 64];
                    acc4[0][tt] = __builtin_amdgcn_mfma_f32_16x16x32_bf16(a0, b, acc4[0][tt], 0, 0, 0);
                    acc4[1][tt] = __builtin_amdgcn_mfma_f32_16x16x32_bf16(a1, b, acc4[1][tt], 0, 0, 0);
                }
            }
            const float* b2l = b2 + l * 128;
            float vv[16], rs[2][4], rq[2][4];
#pragma unroll
            for (int mt = 0; mt < 2; mt++)
#pragma unroll
                for (int r = 0; r < 4; r++) { rs[mt][r] = 0.f; rq[mt][r] = 0.f; }
#pragma unroll
            for (int mt = 0; mt < 2; mt++)
#pragma unroll
                for (int tt = 0; tt < 2; tt++) {
                    int c = cq * 32 + tt * 16 + col;
                    float bv = b2l[c];
#pragma unroll
                    for (int r = 0; r < 4; r++) {
                        float v = acc4[mt][tt][r] + bv + zreg[mt * 8 + tt * 4 + r];
                        vv[mt * 8 + tt * 4 + r] = v;
                        rs[mt][r] += v;
                        rq[mt][r] = fmaf(v, v, rq[mt][r]);
                    }
                }
#pragma unroll
            for (int m = 1; m <= 8; m <<= 1)
#pragma unroll
                for (int mt = 0; mt < 2; mt++)
#pragma unroll
                    for (int r = 0; r < 4; r++) {
                        rs[mt][r] += __shfl_xor(rs[mt][r], m, 64);
                        rq[mt][r] += __shfl_xor(rq[mt][r], m, 64);
                    }
            if (col == 0) {
#pragma unroll
                for (int mt = 0; mt < 2; mt++)
#pragma unroll
                    for (int r = 0; r < 4; r++) {
                        int row = mt * 16 + quad * 4 + r;
                        lnp[((sq * 4 + cq) * 32 + row) * 2] = rs[mt][r];
                        lnp[((sq * 4 + cq) * 32 + row) * 2 + 1] = rq[mt][r];
                    }
            }
            __syncthreads();                 // B6
            const float* gl = ln2g + l * 128;
            const float* bl = ln2b + l * 128;
#pragma unroll
            for (int mt = 0; mt < 2; mt++)
#pragma unroll
                for (int r = 0; r < 4; r++) {
                    int row = mt * 16 + quad * 4 + r;
                    float sm = 0.f, sqs = 0.f;
#pragma unroll
                    for (int q2 = 0; q2 < 4; q2++) {
                        sm += lnp[((sq * 4 + q2) * 32 + row) * 2];
                        sqs += lnp[((sq * 4 + q2) * 32 + row) * 2 + 1];
                    }
                    float mean = sm * (1.0f / 128.0f);
                    float var = sqs * (1.0f / 128.0f) - mean * mean;
                    float iv = rsqrtf(var + 1e-5f);
#pragma unroll
                    for (int tt = 0; tt < 2; tt++) {
                        int c = cq * 32 + tt * 16 + col;
                        float y = (vv[mt * 8 + tt * 4 + r] - mean) * iv * gl[c] + bl[c];
                        zreg[mt * 8 + tt * 4 + r] = y;
                        if (l < 2) zb[sq * 4352 + row * 136 + c] = __float2bfloat16(y);
                        else if (row == 31)
                            zlastb[(size_t)(bn0 + sq) * 128 + c] = __float2bfloat16(y);
                    }
                }
        }
        __syncthreads();                     // B7
    }
}

// ---------------------------------------------------------------------------
// Head (MFMA): out = gelu(zlast @ W1 + b1) @ W2 + b2. Grid 32 x 256 thr.
__global__ __launch_bounds__(256)
void k_head(const bf16* __restrict__ zlastb, const short8* __restrict__ BpHW1,
            const float* __restrict__ b1, const float* __restrict__ W2,
            const float* __restrict__ b2, float* __restrict__ out) {
    __shared__ bf16 h1[16 * 136];
    int blk = blockIdx.x;
    int tid = threadIdx.x;
    int lane = tid & 63, w = tid >> 6;
    int quad = lane >> 4, col = lane & 15;
    {
        floatx4 acc[2];
        acc[0] = (floatx4){0.f, 0.f, 0.f, 0.f};
        acc[1] = (floatx4){0.f, 0.f, 0.f, 0.f};
        const short8* Ap = (const short8*)(zlastb + (size_t)(blk * 16 + col) * 128) + quad;
        for (int kt = 0; kt < 4; kt++) {
            short8 a = Ap[kt * 4];
            const short8* bp = BpHW1 + (size_t)(kt * 8 + w * 2) * 64 + lane;
            acc[0] = __builtin_amdgcn_mfma_f32_16x16x32_bf16(a, bp[0], acc[0], 0, 0, 0);
            acc[1] = __builtin_amdgcn_mfma_f32_16x16x32_bf16(a, bp[64], acc[1], 0, 0, 0);
        }
#pragma unroll
        for (int tt = 0; tt < 2; tt++) {
            int c = w * 32 + tt * 16 + col;
            float bv = b1[c];
#pragma unroll
            for (int r = 0; r < 4; r++)
                h1[(quad * 4 + r) * 136 + c] = __float2bfloat16(gelu_exact(acc[tt][r] + bv));
        }
    }
    __syncthreads();
    if (tid < 96) {
        int row = tid / 6, c = tid % 6;
        float a0 = 0.f, a1 = 0.f, a2 = 0.f, a3 = 0.f;
        const bf16* hr = &h1[row * 136];
#pragma unroll 8
        for (int k = 0; k < 128; k += 4) {
            a0 = fmaf(bfbits2f(*(const short*)&hr[k]),     W2[k * 6 + c], a0);
            a1 = fmaf(bfbits2f(*(const short*)&hr[k + 1]), W2[(k + 1) * 6 + c], a1);
            a2 = fmaf(bfbits2f(*(const short*)&hr[k + 2]), W2[(k + 2) * 6 + c], a2);
            a3 = fmaf(bfbits2f(*(const short*)&hr[k + 3]), W2[(k + 3) * 6 + c], a3);
        }
        out[(size_t)(blk * 16 + row) * 6 + c] = (a0 + a1) + (a2 + a3) + b2[c];
    }
}

// ---------------------------------------------------------------------------
extern "C" void kernel_launch(void* const* d_in, const int* in_sizes, int n_in,
                              void* d_out, int out_size, void* d_ws, size_t ws_size,
                              hipStream_t stream) {
    const float* input_frames = (const float*)d_in[0];
    const float* edge_attr    = (const float*)d_in[1];
    const float* proj_W  = (const float*)d_in[2];
    const float* proj_b  = (const float*)d_in[3];
    const float* sp_Wq   = (const float*)d_in[4];
    const float* sp_bq   = (const float*)d_in[5];
    const float* sp_Wk   = (const float*)d_in[6];
    const float* sp_bk   = (const float*)d_in[7];
    const float* sp_Wv   = (const float*)d_in[8];
    const float* sp_bv   = (const float*)d_in[9];
    const float* sp_We   = (const float*)d_in[10];
    const float* sp_be   = (const float*)d_in[11];
    const float* sp_Ws   = (const float*)d_in[12];
    const float* sp_bs   = (const float*)d_in[13];
    const float* sp_lng  = (const float*)d_in[14];
    const float* sp_lnb  = (const float*)d_in[15];
    const float* tpos    = (const float*)d_in[16];
    const float* t_Wqkv  = (const float*)d_in[17];
    const float* t_bqkv  = (const float*)d_in[18];
    const float* t_Wo    = (const float*)d_in[19];
    const float* t_bo    = (const float*)d_in[20];
    const float* t_ln1g  = (const float*)d_in[21];
    const float* t_ln1b  = (const float*)d_in[22];
    const float* t_W1    = (const float*)d_in[23];
    const float* t_b1    = (const float*)d_in[24];
    const float* t_W2    = (const float*)d_in[25];
    const float* t_b2    = (const float*)d_in[26];
    const float* t_ln2g  = (const float*)d_in[27];
    const float* t_ln2b  = (const float*)d_in[28];
    const float* head_W1 = (const float*)d_in[29];
    const float* head_b1 = (const float*)d_in[30];
    const float* head_W2 = (const float*)d_in[31];
    const float* head_b2 = (const float*)d_in[32];

    float* f     = (float*)d_ws;
    float* z32g  = f;                                  // 2M floats
    bf16*  zlastb = (bf16*)(f + (1u << 21));           // 64K bf16
    float* spb   = f + (1u << 21) + 65536;             // 1152 floats
    bf16* BpBase = (bf16*)(f + (1u << 21) + 65536 + 2048);
    bf16* BpSPQKV = BpBase;                            // 147456 bf16
    bf16* BpWS    = BpSPQKV + 147456;                  //  49152
    bf16* BpTQKV  = BpWS + 49152;                      // 147456
    bf16* BpWO    = BpTQKV + 147456;                   //  49152
    bf16* BpW1    = BpWO + 49152;                      // 196608
    bf16* BpW2    = BpW1 + 196608;                     // 196608
    bf16* BpHW1   = BpW2 + 196608;                     //  16384

    RepackArgs ra;
    int s = 0;
    auto mk = [&](int i, const float* W, bf16* out, int K, int N, int ntt, int ntoff, int L) {
        ra.d[i] = {W, out, K, N, ntt, ntoff, L, s};
        s += L * (K >> 5) * (N >> 4) * 64;
    };
    mk(0, sp_Wq, BpSPQKV, 128, 128, 24, 0, 3);
    mk(1, sp_Wk, BpSPQKV, 128, 128, 24, 8, 3);
    mk(2, sp_Wv, BpSPQKV, 128, 128, 24, 16, 3);
    mk(3, sp_Ws, BpWS, 128, 128, 8, 0, 3);
    mk(4, t_Wqkv, BpTQKV, 128, 384, 24, 0, 3);
    mk(5, t_Wo, BpWO, 128, 128, 8, 0, 3);
    mk(6, t_W1, BpW1, 128, 512, 32, 0, 3);
    mk(7, t_W2, BpW2, 512, 128, 8, 0, 3);
    mk(8, head_W1, BpHW1, 128, 128, 8, 0, 1);
    ra.total = s;
    ra.bq = sp_bq; ra.bk = sp_bk; ra.bv = sp_bv; ra.spb = spb;
    k_repack<<<(s + 1152 + 255) / 256, 256, 0, stream>>>(ra);

    k_spatial3<<<BT_, 512, 0, stream>>>(
        input_frames, proj_W, proj_b,
        (const short8*)BpSPQKV, (const short8*)BpWS,
        spb, sp_bs, sp_lng, sp_lnb, edge_attr, sp_We, sp_be, tpos, z32g);

    k_temporal3<<<BN_ / 2, 512, 0, stream>>>(
        z32g, (const short8*)BpTQKV, (const short8*)BpWO,
        (const short8*)BpW1, (const short8*)BpW2,
        t_bqkv, t_bo, t_ln1g, t_ln1b, t_b1, t_b2, t_ln2g, t_ln2b, zlastb);

    k_head<<<32, 256, 0, stream>>>(zlastb, (const short8*)BpHW1, head_b1,
                                   head_W2, head_b2, (float*)d_out);
}

// Round 13
// 280.388 us; speedup vs baseline: 1.0440x; 1.0440x over previous
//
#include <hip/hip_runtime.h>
#include <hip/hip_bf16.h>
#include <math.h>

typedef __hip_bfloat16 bf16;
typedef short short8 __attribute__((ext_vector_type(8)));
typedef float floatx4 __attribute__((ext_vector_type(4)));

#define B_    8
#define T_    32
#define N_    64
#define F_    6
#define D_    128
#define E_    4032      // N*(N-1)
#define BT_   256       // B*T
#define BN_   512       // B*N

__device__ __forceinline__ float gelu_exact(float x) {
    return 0.5f * x * (1.0f + erff(x * 0.70710678118654752f));
}
__device__ __forceinline__ float bfbits2f(short s) {
    unsigned int u = ((unsigned int)(unsigned short)s) << 16;
    return __uint_as_float(u);
}
// load 32 consecutive bf16 from LDS (16B-aligned) as fp32
__device__ __forceinline__ void ld32lds(const bf16* p, float* o) {
    const short8* sp = (const short8*)p;
#pragma unroll
    for (int i = 0; i < 4; i++) {
        short8 s = sp[i];
#pragma unroll
        for (int j = 0; j < 8; j++) o[i * 8 + j] = bfbits2f(s[j]);
    }
}

// ---------------------------------------------------------------------------
// Repack weights into MFMA B-fragment layout + pack spatial qkv biases.
struct RepackDesc { const float* W; bf16* out; int K, N, ntt, ntoff, L, start; };
struct RepackArgs {
    RepackDesc d[9]; int total;
    const float *bq, *bk, *bv; float* spb;
};

__global__ void k_repack(RepackArgs ra) {
    int gid = blockIdx.x * blockDim.x + threadIdx.x;
    if (gid >= ra.total) {
        int i = gid - ra.total;
        if (i < 3 * 384) {
            int l = i / 384, c = i % 384;
            float v = (c < 128) ? ra.bq[l * 128 + c]
                    : (c < 256) ? ra.bk[l * 128 + c - 128]
                                : ra.bv[l * 128 + c - 256];
            ra.spb[i] = v;
        }
        return;
    }
    int fi = 0;
    while (fi < 8 && gid >= ra.d[fi + 1].start) fi++;
    RepackDesc dd = ra.d[fi];
    int r = gid - dd.start;
    int lane = r & 63; r >>= 6;
    int ntiles = dd.N >> 4;
    int nt = r % ntiles; r /= ntiles;
    int ktiles = dd.K >> 5;
    int kt = r % ktiles;
    int l = r / ktiles;
    int quad = lane >> 4, cc = lane & 15;
    const float* Wl = dd.W + (size_t)l * dd.K * dd.N;
    bf16* o = dd.out + ((((size_t)l * ktiles + kt) * dd.ntt + nt + dd.ntoff) * 64 + lane) * 8;
    int kb = kt * 32 + quad * 8;
    int n = nt * 16 + cc;
#pragma unroll
    for (int j = 0; j < 8; j++)
        o[j] = __float2bfloat16(Wl[(size_t)(kb + j) * dd.N + n]);
}

// ---------------------------------------------------------------------------
// FUSED 3-layer spatial stack. One block per (b,t) graph, 512 thr = 8 waves.
// Dedicated padded aggf region (no qk overlay) -> 3 barriers/layer.
// NO register prefetch (R10 lesson: spills under launch_bounds).
__global__ __launch_bounds__(512, 1)
void k_spatial3(const float* __restrict__ inp, const float* __restrict__ projW,
                const float* __restrict__ projB,
                const short8* __restrict__ BpQKV, const short8* __restrict__ BpWS,
                const float* __restrict__ spb, const float* __restrict__ bs,
                const float* __restrict__ lng, const float* __restrict__ lnb,
                const float* __restrict__ ea, const float* __restrict__ Weg,
                const float* __restrict__ beg, const float* __restrict__ tpos,
                float* __restrict__ z32g) {
    __shared__ short smem[78208];            // 156416 B
    bf16* hb = (bf16*)smem;                  // [0,8704)s: 64 x 136
    bf16* qk = (bf16*)(smem + 8704);         // 64 x 264 (q|k)
    bf16* Vt = (bf16*)(smem + 25600);        // 128 x 72 (d-major)
    bf16* Ps = (bf16*)(smem + 34816);        // h*4608 + m*72
    float* aggf = (float*)(smem + 53248);    // 64 x 132 fp32 (dedicated)
    float* fsm = aggf;                       // proj staging overlay
    float* EAs = (float*)(smem + 70144);     // 4032 fp32

    int bt = blockIdx.x;
    int tid = threadIdx.x;
    int lane = tid & 63, w = tid >> 6;
    int quad = lane >> 4, col = lane & 15;
    int w4 = w & 3, wh = w >> 2;
    const float scale = 0.17677669529663687f;   // 1/sqrt(32)

    for (int i = tid; i < 896; i += 512)
        fsm[i] = (i < 768) ? projW[i] : projB[i - 768];
    {
        const float* eag = ea + (size_t)bt * E_;
        for (int i = tid; i < E_; i += 512) EAs[i] = eag[i];
    }
    __syncthreads();
    float hreg[32];
    if (w < 4) {
#pragma unroll
        for (int r = 0; r < 4; r++) {
            int n = w * 16 + quad * 4 + r;
            const float* xr = inp + (size_t)(bt * 64 + n) * F_;
            float xin[6];
#pragma unroll
            for (int k2 = 0; k2 < 6; k2++) xin[k2] = xr[k2];
#pragma unroll
            for (int tt = 0; tt < 8; tt++) {
                int c = tt * 16 + col;
                float a = fsm[768 + c];
#pragma unroll
                for (int k2 = 0; k2 < 6; k2++) a = fmaf(xin[k2], fsm[k2 * 128 + c], a);
                hreg[tt * 4 + r] = a;
                hb[n * 136 + c] = __float2bfloat16(a);
            }
        }
    }
    __syncthreads();                         // B0

    for (int l = 0; l < 3; l++) {
        // ---- phase 1: qkv GEMM ----
        {
            floatx4 acc[12];
#pragma unroll
            for (int tt = 0; tt < 12; tt++) acc[tt] = (floatx4){0.f, 0.f, 0.f, 0.f};
            const short8* bpl = BpQKV + (size_t)l * 6144;
            for (int kt = 0; kt < 4; kt++) {
                short8 a = *(const short8*)&hb[(w4 * 16 + col) * 136 + kt * 32 + quad * 8];
                const short8* bp = bpl + (size_t)(kt * 24 + wh * 12) * 64 + lane;
#pragma unroll
                for (int tt = 0; tt < 12; tt++)
                    acc[tt] = __builtin_amdgcn_mfma_f32_16x16x32_bf16(a, bp[tt * 64], acc[tt], 0, 0, 0);
            }
            const float* bias = spb + l * 384;
#pragma unroll
            for (int tt = 0; tt < 12; tt++) {
                int c = wh * 192 + tt * 16 + col;
                float bv = bias[c];
#pragma unroll
                for (int r = 0; r < 4; r++) {
                    int row = w4 * 16 + quad * 4 + r;
                    bf16 v = __float2bfloat16(acc[tt][r] + bv);
                    if (c < 256) qk[row * 264 + c] = v;
                    else         Vt[(c - 256) * 72 + row] = v;
                }
            }
        }
        __syncthreads();                     // B1: qk/Vt visible
        // ---- phase 2: attention (no barrier until aggf done) ----
        int h = w4, half = wh;
        int hoff = h * 32;
        const float* Wel = Weg + l * 128 + hoff;
        const float* bel = beg + l * 128 + hoff;
        float qWe;
        {
            int dst = half * 32 + (lane & 31);
            float qr[32];
            ld32lds(&qk[dst * 264 + hoff], qr);
            float s0 = 0.f, s1 = 0.f, s2 = 0.f, s3 = 0.f;
#pragma unroll
            for (int c2 = 0; c2 < 32; c2 += 4) {
                s0 = fmaf(qr[c2], Wel[c2], s0);
                s1 = fmaf(qr[c2 + 1], Wel[c2 + 1], s1);
                s2 = fmaf(qr[c2 + 2], Wel[c2 + 2], s2);
                s3 = fmaf(qr[c2 + 3], Wel[c2 + 3], s3);
            }
            qWe = (s0 + s1) + (s2 + s3);
        }
        float s[2][4][4], ev[2][4][4];
        {
            short8 aA[2], bB[4];
#pragma unroll
            for (int mtl = 0; mtl < 2; mtl++)
                aA[mtl] = *(const short8*)&qk[((half * 2 + mtl) * 16 + col) * 264 + hoff + quad * 8];
#pragma unroll
            for (int nt = 0; nt < 4; nt++)
                bB[nt] = *(const short8*)&qk[(nt * 16 + col) * 264 + 128 + hoff + quad * 8];
#pragma unroll
            for (int mtl = 0; mtl < 2; mtl++)
#pragma unroll
                for (int nt = 0; nt < 4; nt++) {
                    floatx4 acc = (floatx4){0.f, 0.f, 0.f, 0.f};
                    acc = __builtin_amdgcn_mfma_f32_16x16x32_bf16(aA[mtl], bB[nt], acc, 0, 0, 0);
#pragma unroll
                    for (int r = 0; r < 4; r++) s[mtl][nt][r] = acc[r];
                }
        }
        float ls[2][4], ae[2][4], inv[2][4];
#pragma unroll
        for (int mtl = 0; mtl < 2; mtl++)
#pragma unroll
            for (int r = 0; r < 4; r++) {
                int m = half * 32 + mtl * 16 + quad * 4 + r;
                float qWeR = __shfl(qWe, mtl * 16 + quad * 4 + r, 64);
                float rmax = -1e30f;
#pragma unroll
                for (int nt = 0; nt < 4; nt++) {
                    int n = nt * 16 + col;
                    bool diag = (m == n);
                    int eid = diag ? 0 : (n * 63 + m - (m > n ? 1 : 0));
                    float eav = diag ? 0.f : EAs[eid];
                    ev[mtl][nt][r] = eav;
                    float al = diag ? -1e30f
                                    : scale * (s[mtl][nt][r] + eav * qWeR);
                    s[mtl][nt][r] = al;
                    rmax = fmaxf(rmax, al);
                }
#pragma unroll
                for (int mk2 = 1; mk2 <= 8; mk2 <<= 1)
                    rmax = fmaxf(rmax, __shfl_xor(rmax, mk2, 64));
                float lsum = 0.f, aesum = 0.f;
#pragma unroll
                for (int nt = 0; nt < 4; nt++) {
                    float p = __expf(s[mtl][nt][r] - rmax);
                    s[mtl][nt][r] = p;
                    lsum += p;
                    aesum = fmaf(p, ev[mtl][nt][r], aesum);
                }
#pragma unroll
                for (int mk2 = 1; mk2 <= 8; mk2 <<= 1) {
                    lsum += __shfl_xor(lsum, mk2, 64);
                    aesum += __shfl_xor(aesum, mk2, 64);
                }
                ls[mtl][r] = lsum;
                ae[mtl][r] = aesum;
                inv[mtl][r] = 1.0f / lsum;
            }
        // PV: P hi/lo compensated bf16 split (Ps wave-private)
        bf16* PsH = Ps + h * 4608;
        floatx4 oacc[2][2];
#pragma unroll
        for (int mtl = 0; mtl < 2; mtl++)
#pragma unroll
            for (int ntB = 0; ntB < 2; ntB++) oacc[mtl][ntB] = (floatx4){0.f, 0.f, 0.f, 0.f};
#pragma unroll
        for (int p = 0; p < 2; p++) {
#pragma unroll
            for (int mtl = 0; mtl < 2; mtl++)
#pragma unroll
                for (int q2 = 0; q2 < 2; q2++) {
                    int nl = q2 * 16 + col;
                    int base0 = (half * 32 + mtl * 16 + quad * 4) * 72 + ((nl >> 3) * 2) * 8 + (nl & 7);
#pragma unroll
                    for (int r = 0; r < 4; r++) {
                        float p_ = s[mtl][2 * p + q2][r];
                        bf16 hi = __float2bfloat16(p_);
                        bf16 lo = __float2bfloat16(p_ - bfbits2f(*(short*)&hi));
                        PsH[base0 + r * 72] = hi;
                        PsH[base0 + r * 72 + 8] = lo;
                    }
                }
            short8 aPh[2], aPl[2], bV[2];
#pragma unroll
            for (int mtl = 0; mtl < 2; mtl++) {
                int rb = (half * 32 + mtl * 16 + col) * 72 + quad * 16;
                aPh[mtl] = *(const short8*)&PsH[rb];
                aPl[mtl] = *(const short8*)&PsH[rb + 8];
            }
#pragma unroll
            for (int ntB = 0; ntB < 2; ntB++)
                bV[ntB] = *(const short8*)&Vt[(hoff + ntB * 16 + col) * 72 + p * 32 + quad * 8];
#pragma unroll
            for (int mtl = 0; mtl < 2; mtl++)
#pragma unroll
                for (int ntB = 0; ntB < 2; ntB++) {
                    oacc[mtl][ntB] = __builtin_amdgcn_mfma_f32_16x16x32_bf16(aPh[mtl], bV[ntB], oacc[mtl][ntB], 0, 0, 0);
                    oacc[mtl][ntB] = __builtin_amdgcn_mfma_f32_16x16x32_bf16(aPl[mtl], bV[ntB], oacc[mtl][ntB], 0, 0, 0);
                }
        }
#pragma unroll
        for (int mtl = 0; mtl < 2; mtl++)
#pragma unroll
            for (int ntB = 0; ntB < 2; ntB++) {
                int c = hoff + ntB * 16 + col;
                float Wc = Wel[ntB * 16 + col];
                float bc = bel[ntB * 16 + col];
#pragma unroll
                for (int r = 0; r < 4; r++) {
                    int m = half * 32 + mtl * 16 + quad * 4 + r;
                    aggf[m * 132 + c] = fmaf(fmaf(ae[mtl][r], Wc, oacc[mtl][ntB][r]),
                                             inv[mtl][r], bc);
                }
            }
        __syncthreads();                     // B2: agg visible (qk reads also done)
        // ---- epilogue: Ws GEMM + agg + residual + LN (waves 0-3) ----
        if (w < 4) {
            floatx4 acc2[8];
#pragma unroll
            for (int tt = 0; tt < 8; tt++) acc2[tt] = (floatx4){0.f, 0.f, 0.f, 0.f};
            const short8* bpl = BpWS + (size_t)l * 2048;
            for (int kt = 0; kt < 4; kt++) {
                short8 a = *(const short8*)&hb[(w * 16 + col) * 136 + kt * 32 + quad * 8];
                const short8* bp = bpl + (size_t)(kt * 8) * 64 + lane;
#pragma unroll
                for (int tt = 0; tt < 8; tt++)
                    acc2[tt] = __builtin_amdgcn_mfma_f32_16x16x32_bf16(a, bp[tt * 64], acc2[tt], 0, 0, 0);
            }
            const float* bsl = bs + l * 128;
            float vv[32], rs[4] = {0.f, 0.f, 0.f, 0.f};
#pragma unroll
            for (int tt = 0; tt < 8; tt++) {
                int c = tt * 16 + col;
                float bv = bsl[c];
#pragma unroll
                for (int r = 0; r < 4; r++) {
                    int row = w * 16 + quad * 4 + r;
                    float v = acc2[tt][r] + bv + aggf[row * 132 + c] + hreg[tt * 4 + r];
                    vv[tt * 4 + r] = v;
                    rs[r] += v;
                }
            }
#pragma unroll
            for (int m = 1; m <= 8; m <<= 1)
#pragma unroll
                for (int r = 0; r < 4; r++) rs[r] += __shfl_xor(rs[r], m, 64);
            float mean[4], vs[4] = {0.f, 0.f, 0.f, 0.f};
#pragma unroll
            for (int r = 0; r < 4; r++) mean[r] = rs[r] * (1.0f / 128.0f);
#pragma unroll
            for (int i = 0; i < 32; i++) {
                float d = vv[i] - mean[i & 3];
                vv[i] = d;
                vs[i & 3] += d * d;
            }
#pragma unroll
            for (int m = 1; m <= 8; m <<= 1)
#pragma unroll
                for (int r = 0; r < 4; r++) vs[r] += __shfl_xor(vs[r], m, 64);
            float inv2[4];
#pragma unroll
            for (int r = 0; r < 4; r++) inv2[r] = rsqrtf(vs[r] * (1.0f / 128.0f) + 1e-5f);
            const float* gl = lng + l * 128;
            const float* bl = lnb + l * 128;
            if (l < 2) {
#pragma unroll
                for (int tt = 0; tt < 8; tt++) {
                    int c = tt * 16 + col;
                    float gc = gl[c], bc = bl[c];
#pragma unroll
                    for (int r = 0; r < 4; r++) {
                        float y = vv[tt * 4 + r] * inv2[r] * gc + bc;
                        int n = w * 16 + quad * 4 + r;
                        hreg[tt * 4 + r] = y;
                        hb[n * 136 + c] = __float2bfloat16(y);
                    }
                }
            } else {
                int b = bt >> 5, t_ = bt & 31;
#pragma unroll
                for (int tt = 0; tt < 8; tt++) {
                    int c = tt * 16 + col;
                    float gc = gl[c], bc = bl[c], pc = tpos[t_ * 128 + c];
#pragma unroll
                    for (int r = 0; r < 4; r++) {
                        float y = vv[tt * 4 + r] * inv2[r] * gc + bc;
                        int n = w * 16 + quad * 4 + r;
                        z32g[((size_t)(b * 64 + n) * 32 + t_) * 128 + c] = y + pc;
                    }
                }
            }
        }
        __syncthreads();                     // B3: layer complete
    }
}

// ---------------------------------------------------------------------------
// FUSED 3-layer temporal stack (round-11 proven version, 96.2 us). One block
// per (b,n) sequence, 512 thr = 8 waves, all active; LN via cross-wave LDS
// partials. 64 KB LDS -> 2 blocks/CU (load-bearing: cross-block overlap).
__global__ __launch_bounds__(512, 4)
void k_temporal3(const float* __restrict__ z32g,
                 const short8* __restrict__ BpQKV, const short8* __restrict__ BpWO,
                 const short8* __restrict__ BpW1, const short8* __restrict__ BpW2,
                 const float* __restrict__ bqkv, const float* __restrict__ bo,
                 const float* __restrict__ ln1g, const float* __restrict__ ln1b,
                 const float* __restrict__ b1, const float* __restrict__ b2,
                 const float* __restrict__ ln2g, const float* __restrict__ ln2b,
                 bf16* __restrict__ zlastb) {
    __shared__ short smem[32000];            // 64000 B
    bf16* zb  = (bf16*)smem;                 // [0,4352)s: 32 x 136
    bf16* qk  = (bf16*)(smem + 4352);        // 32 x 264
    bf16* Ps  = (bf16*)(smem + 12800);       // (h*2+mh)*1152
    bf16* Vt  = (bf16*)(smem + 22016);       // d*40 + t
    bf16* o16 = (bf16*)(smem + 27136);       // 32 x 136
    float* lnp = (float*)(smem + 31488);     // 4x32x2 fp32
    bf16* f1  = (bf16*)(smem + 4352);        // overlay: 32 x 520

    int bn = blockIdx.x;
    int tid = threadIdx.x;
    int lane = tid & 63, w = tid >> 6;
    int quad = lane >> 4, col = lane & 15;
    int mt = w & 1, cq = w >> 1;
    const float scale = 0.17677669529663687f;

    for (int i = tid; i < 4096; i += 512) {
        float v = z32g[(size_t)bn * 4096 + i];
        zb[(i >> 7) * 136 + (i & 127)] = __float2bfloat16(v);
    }
    float zreg[8];
#pragma unroll
    for (int t2 = 0; t2 < 2; t2++)
#pragma unroll
        for (int r = 0; r < 4; r++)
            zreg[t2 * 4 + r] = z32g[(size_t)bn * 4096 +
                                    (mt * 16 + quad * 4 + r) * 128 + cq * 32 + t2 * 16 + col];
    __syncthreads();

    for (int l = 0; l < 3; l++) {
        // ---- phase 1: qkv GEMM ----
        {
            floatx4 acc[6];
#pragma unroll
            for (int tt = 0; tt < 6; tt++) acc[tt] = (floatx4){0.f, 0.f, 0.f, 0.f};
            const short8* bpl = BpQKV + (size_t)l * 6144;
            for (int kt = 0; kt < 4; kt++) {
                short8 a = *(const short8*)&zb[(mt * 16 + col) * 136 + kt * 32 + quad * 8];
                const short8* bp = bpl + (size_t)(kt * 24 + cq * 6) * 64 + lane;
#pragma unroll
                for (int tt = 0; tt < 6; tt++)
                    acc[tt] = __builtin_amdgcn_mfma_f32_16x16x32_bf16(a, bp[tt * 64], acc[tt], 0, 0, 0);
            }
            const float* bias = bqkv + l * 384;
#pragma unroll
            for (int tt = 0; tt < 6; tt++) {
                int c = cq * 96 + tt * 16 + col;
                float bv = bias[c];
#pragma unroll
                for (int r = 0; r < 4; r++) {
                    int row = mt * 16 + quad * 4 + r;
                    bf16 v = __float2bfloat16(acc[tt][r] + bv);
                    if (c < 256) qk[row * 264 + c] = v;
                    else         Vt[(c - 256) * 40 + row] = v;
                }
            }
        }
        __syncthreads();                     // B1
        // ---- phase 2: attention. wave=(h=w&3, mh=w>>2) ----
        {
            int h = w & 3, mh = w >> 2;
            int hoff = h * 32;
            bf16* PsH = Ps + (h * 2 + mh) * 1152;
            float s[2][4];
            short8 aA = *(const short8*)&qk[(mh * 16 + col) * 264 + hoff + quad * 8];
            short8 bB[2];
#pragma unroll
            for (int nt = 0; nt < 2; nt++)
                bB[nt] = *(const short8*)&qk[(nt * 16 + col) * 264 + 128 + hoff + quad * 8];
#pragma unroll
            for (int nt = 0; nt < 2; nt++) {
                floatx4 acc = (floatx4){0.f, 0.f, 0.f, 0.f};
                acc = __builtin_amdgcn_mfma_f32_16x16x32_bf16(aA, bB[nt], acc, 0, 0, 0);
#pragma unroll
                for (int r = 0; r < 4; r++) s[nt][r] = acc[r];
            }
            float inv[4];
#pragma unroll
            for (int r = 0; r < 4; r++) {
                int m = mh * 16 + quad * 4 + r;
                float rmax = -1e30f;
#pragma unroll
                for (int nt = 0; nt < 2; nt++) {
                    int n = nt * 16 + col;
                    float al = (n > m) ? -1e30f : s[nt][r] * scale;
                    s[nt][r] = al;
                    rmax = fmaxf(rmax, al);
                }
#pragma unroll
                for (int mk2 = 1; mk2 <= 8; mk2 <<= 1)
                    rmax = fmaxf(rmax, __shfl_xor(rmax, mk2, 64));
                float lsum = 0.f;
#pragma unroll
                for (int nt = 0; nt < 2; nt++) {
                    float p = __expf(s[nt][r] - rmax);
                    s[nt][r] = p;
                    lsum += p;
                }
#pragma unroll
                for (int mk2 = 1; mk2 <= 8; mk2 <<= 1)
                    lsum += __shfl_xor(lsum, mk2, 64);
                inv[r] = 1.0f / lsum;
            }
#pragma unroll
            for (int nt = 0; nt < 2; nt++) {
                int n = nt * 16 + col;
                int base0 = (quad * 4) * 72 + ((n >> 3) * 2) * 8 + (n & 7);
#pragma unroll
                for (int r = 0; r < 4; r++) {
                    float p_ = s[nt][r];
                    bf16 hi = __float2bfloat16(p_);
                    bf16 lo = __float2bfloat16(p_ - bfbits2f(*(short*)&hi));
                    PsH[base0 + r * 72] = hi;
                    PsH[base0 + r * 72 + 8] = lo;
                }
            }
            floatx4 oacc[2];
#pragma unroll
            for (int nt = 0; nt < 2; nt++) oacc[nt] = (floatx4){0.f, 0.f, 0.f, 0.f};
            short8 aPh = *(const short8*)&PsH[col * 72 + quad * 16];
            short8 aPl = *(const short8*)&PsH[col * 72 + quad * 16 + 8];
            short8 bV[2];
#pragma unroll
            for (int nt = 0; nt < 2; nt++)
                bV[nt] = *(const short8*)&Vt[(hoff + nt * 16 + col) * 40 + quad * 8];
#pragma unroll
            for (int nt = 0; nt < 2; nt++) {
                oacc[nt] = __builtin_amdgcn_mfma_f32_16x16x32_bf16(aPh, bV[nt], oacc[nt], 0, 0, 0);
                oacc[nt] = __builtin_amdgcn_mfma_f32_16x16x32_bf16(aPl, bV[nt], oacc[nt], 0, 0, 0);
            }
#pragma unroll
            for (int nt = 0; nt < 2; nt++) {
                int c = hoff + nt * 16 + col;
#pragma unroll
                for (int r = 0; r < 4; r++)
                    o16[(mh * 16 + quad * 4 + r) * 136 + c] =
                        __float2bfloat16(oacc[nt][r] * inv[r]);
            }
        }
        __syncthreads();                     // B2
        // ---- Wo GEMM + residual + LN1: wave=(mt, cq), 2 tiles ----
        {
            floatx4 acc2[2];
#pragma unroll
            for (int tt = 0; tt < 2; tt++) acc2[tt] = (floatx4){0.f, 0.f, 0.f, 0.f};
            const short8* bpl = BpWO + (size_t)l * 2048;
            for (int kt = 0; kt < 4; kt++) {
                short8 a = *(const short8*)&o16[(mt * 16 + col) * 136 + kt * 32 + quad * 8];
                const short8* bp = bpl + (size_t)(kt * 8 + cq * 2) * 64 + lane;
#pragma unroll
                for (int tt = 0; tt < 2; tt++)
                    acc2[tt] = __builtin_amdgcn_mfma_f32_16x16x32_bf16(a, bp[tt * 64], acc2[tt], 0, 0, 0);
            }
            const float* bol = bo + l * 128;
            float vv[8], rs[4] = {0.f, 0.f, 0.f, 0.f}, rq[4] = {0.f, 0.f, 0.f, 0.f};
#pragma unroll
            for (int tt = 0; tt < 2; tt++) {
                int c = cq * 32 + tt * 16 + col;
                float bv = bol[c];
#pragma unroll
                for (int r = 0; r < 4; r++) {
                    float v = acc2[tt][r] + bv + zreg[tt * 4 + r];
                    vv[tt * 4 + r] = v;
                    rs[r] += v;
                    rq[r] = fmaf(v, v, rq[r]);
                }
            }
#pragma unroll
            for (int m = 1; m <= 8; m <<= 1)
#pragma unroll
                for (int r = 0; r < 4; r++) {
                    rs[r] += __shfl_xor(rs[r], m, 64);
                    rq[r] += __shfl_xor(rq[r], m, 64);
                }
            if (col == 0) {
#pragma unroll
                for (int r = 0; r < 4; r++) {
                    int row = mt * 16 + quad * 4 + r;
                    lnp[(cq * 32 + row) * 2] = rs[r];
                    lnp[(cq * 32 + row) * 2 + 1] = rq[r];
                }
            }
            __syncthreads();                 // B3
            const float* gl = ln1g + l * 128;
            const float* bl = ln1b + l * 128;
#pragma unroll
            for (int r = 0; r < 4; r++) {
                int row = mt * 16 + quad * 4 + r;
                float sm = 0.f, sq = 0.f;
#pragma unroll
                for (int q2 = 0; q2 < 4; q2++) {
                    sm += lnp[(q2 * 32 + row) * 2];
                    sq += lnp[(q2 * 32 + row) * 2 + 1];
                }
                float mean = sm * (1.0f / 128.0f);
                float var = sq * (1.0f / 128.0f) - mean * mean;
                float iv = rsqrtf(var + 1e-5f);
#pragma unroll
                for (int tt = 0; tt < 2; tt++) {
                    int c = cq * 32 + tt * 16 + col;
                    float y = (vv[tt * 4 + r] - mean) * iv * gl[c] + bl[c];
                    zreg[tt * 4 + r] = y;
                    zb[row * 136 + c] = __float2bfloat16(y);
                }
            }
        }
        __syncthreads();                     // B4
        // ---- W1 GEMM + gelu ----
        {
            floatx4 acc3[8];
#pragma unroll
            for (int tt = 0; tt < 8; tt++) acc3[tt] = (floatx4){0.f, 0.f, 0.f, 0.f};
            const short8* bpl = BpW1 + (size_t)l * 8192;
            for (int kt = 0; kt < 4; kt++) {
                short8 a = *(const short8*)&zb[(mt * 16 + col) * 136 + kt * 32 + quad * 8];
                const short8* bp = bpl + (size_t)(kt * 32 + cq * 8) * 64 + lane;
#pragma unroll
                for (int tt = 0; tt < 8; tt++)
                    acc3[tt] = __builtin_amdgcn_mfma_f32_16x16x32_bf16(a, bp[tt * 64], acc3[tt], 0, 0, 0);
            }
            const float* b1l = b1 + l * 512;
#pragma unroll
            for (int tt = 0; tt < 8; tt++) {
                int c = cq * 128 + tt * 16 + col;
                float bv = b1l[c];
#pragma unroll
                for (int r = 0; r < 4; r++) {
                    float v = gelu_exact(acc3[tt][r] + bv);
                    f1[(mt * 16 + quad * 4 + r) * 520 + c] = __float2bfloat16(v);
                }
            }
        }
        __syncthreads();                     // B5
        // ---- W2 GEMM + residual + LN2 ----
        {
            floatx4 acc4[2];
#pragma unroll
            for (int tt = 0; tt < 2; tt++) acc4[tt] = (floatx4){0.f, 0.f, 0.f, 0.f};
            const short8* bpl = BpW2 + (size_t)l * 8192;
            for (int kt = 0; kt < 16; kt++) {
                short8 a = *(const short8*)&f1[(mt * 16 + col) * 520 + kt * 32 + quad * 8];
                const short8* bp = bpl + (size_t)(kt * 8 + cq * 2) * 64 + lane;
#pragma unroll
                for (int tt = 0; tt < 2; tt++)
                    acc4[tt] = __builtin_amdgcn_mfma_f32_16x16x32_bf16(a, bp[tt * 64], acc4[tt], 0, 0, 0);
            }
            const float* b2l = b2 + l * 128;
            float vv[8], rs[4] = {0.f, 0.f, 0.f, 0.f}, rq[4] = {0.f, 0.f, 0.f, 0.f};
#pragma unroll
            for (int tt = 0; tt < 2; tt++) {
                int c = cq * 32 + tt * 16 + col;
                float bv = b2l[c];
#pragma unroll
                for (int r = 0; r < 4; r++) {
                    float v = acc4[tt][r] + bv + zreg[tt * 4 + r];
                    vv[tt * 4 + r] = v;
                    rs[r] += v;
                    rq[r] = fmaf(v, v, rq[r]);
                }
            }
#pragma unroll
            for (int m = 1; m <= 8; m <<= 1)
#pragma unroll
                for (int r = 0; r < 4; r++) {
                    rs[r] += __shfl_xor(rs[r], m, 64);
                    rq[r] += __shfl_xor(rq[r], m, 64);
                }
            if (col == 0) {
#pragma unroll
                for (int r = 0; r < 4; r++) {
                    int row = mt * 16 + quad * 4 + r;
                    lnp[(cq * 32 + row) * 2] = rs[r];
                    lnp[(cq * 32 + row) * 2 + 1] = rq[r];
                }
            }
            __syncthreads();                 // B6
            const float* gl = ln2g + l * 128;
            const float* bl = ln2b + l * 128;
#pragma unroll
            for (int r = 0; r < 4; r++) {
                int row = mt * 16 + quad * 4 + r;
                float sm = 0.f, sq = 0.f;
#pragma unroll
                for (int q2 = 0; q2 < 4; q2++) {
                    sm += lnp[(q2 * 32 + row) * 2];
                    sq += lnp[(q2 * 32 + row) * 2 + 1];
                }
                float mean = sm * (1.0f / 128.0f);
                float var = sq * (1.0f / 128.0f) - mean * mean;
                float iv = rsqrtf(var + 1e-5f);
#pragma unroll
                for (int tt = 0; tt < 2; tt++) {
                    int c = cq * 32 + tt * 16 + col;
                    float y = (vv[tt * 4 + r] - mean) * iv * gl[c] + bl[c];
                    zreg[tt * 4 + r] = y;
                    if (l < 2) zb[row * 136 + c] = __float2bfloat16(y);
                    else if (row == 31) zlastb[(size_t)bn * 128 + c] = __float2bfloat16(y);
                }
            }
        }
        __syncthreads();                     // B7
    }
}

// ---------------------------------------------------------------------------
// Head (MFMA): out = gelu(zlast @ W1 + b1) @ W2 + b2. Grid 32 x 256 thr.
__global__ __launch_bounds__(256)
void k_head(const bf16* __restrict__ zlastb, const short8* __restrict__ BpHW1,
            const float* __restrict__ b1, const float* __restrict__ W2,
            const float* __restrict__ b2, float* __restrict__ out) {
    __shared__ bf16 h1[16 * 136];
    int blk = blockIdx.x;
    int tid = threadIdx.x;
    int lane = tid & 63, w = tid >> 6;
    int quad = lane >> 4, col = lane & 15;
    {
        floatx4 acc[2];
        acc[0] = (floatx4){0.f, 0.f, 0.f, 0.f};
        acc[1] = (floatx4){0.f, 0.f, 0.f, 0.f};
        const short8* Ap = (const short8*)(zlastb + (size_t)(blk * 16 + col) * 128) + quad;
        for (int kt = 0; kt < 4; kt++) {
            short8 a = Ap[kt * 4];
            const short8* bp = BpHW1 + (size_t)(kt * 8 + w * 2) * 64 + lane;
            acc[0] = __builtin_amdgcn_mfma_f32_16x16x32_bf16(a, bp[0], acc[0], 0, 0, 0);
            acc[1] = __builtin_amdgcn_mfma_f32_16x16x32_bf16(a, bp[64], acc[1], 0, 0, 0);
        }
#pragma unroll
        for (int tt = 0; tt < 2; tt++) {
            int c = w * 32 + tt * 16 + col;
            float bv = b1[c];
#pragma unroll
            for (int r = 0; r < 4; r++)
                h1[(quad * 4 + r) * 136 + c] = __float2bfloat16(gelu_exact(acc[tt][r] + bv));
        }
    }
    __syncthreads();
    if (tid < 96) {
        int row = tid / 6, c = tid % 6;
        float a0 = 0.f, a1 = 0.f, a2 = 0.f, a3 = 0.f;
        const bf16* hr = &h1[row * 136];
#pragma unroll 8
        for (int k = 0; k < 128; k += 4) {
            a0 = fmaf(bfbits2f(*(const short*)&hr[k]),     W2[k * 6 + c], a0);
            a1 = fmaf(bfbits2f(*(const short*)&hr[k + 1]), W2[(k + 1) * 6 + c], a1);
            a2 = fmaf(bfbits2f(*(const short*)&hr[k + 2]), W2[(k + 2) * 6 + c], a2);
            a3 = fmaf(bfbits2f(*(const short*)&hr[k + 3]), W2[(k + 3) * 6 + c], a3);
        }
        out[(size_t)(blk * 16 + row) * 6 + c] = (a0 + a1) + (a2 + a3) + b2[c];
    }
}

// ---------------------------------------------------------------------------
extern "C" void kernel_launch(void* const* d_in, const int* in_sizes, int n_in,
                              void* d_out, int out_size, void* d_ws, size_t ws_size,
                              hipStream_t stream) {
    const float* input_frames = (const float*)d_in[0];
    const float* edge_attr    = (const float*)d_in[1];
    const float* proj_W  = (const float*)d_in[2];
    const float* proj_b  = (const float*)d_in[3];
    const float* sp_Wq   = (const float*)d_in[4];
    const float* sp_bq   = (const float*)d_in[5];
    const float* sp_Wk   = (const float*)d_in[6];
    const float* sp_bk   = (const float*)d_in[7];
    const float* sp_Wv   = (const float*)d_in[8];
    const float* sp_bv   = (const float*)d_in[9];
    const float* sp_We   = (const float*)d_in[10];
    const float* sp_be   = (const float*)d_in[11];
    const float* sp_Ws   = (const float*)d_in[12];
    const float* sp_bs   = (const float*)d_in[13];
    const float* sp_lng  = (const float*)d_in[14];
    const float* sp_lnb  = (const float*)d_in[15];
    const float* tpos    = (const float*)d_in[16];
    const float* t_Wqkv  = (const float*)d_in[17];
    const float* t_bqkv  = (const float*)d_in[18];
    const float* t_Wo    = (const float*)d_in[19];
    const float* t_bo    = (const float*)d_in[20];
    const float* t_ln1g  = (const float*)d_in[21];
    const float* t_ln1b  = (const float*)d_in[22];
    const float* t_W1    = (const float*)d_in[23];
    const float* t_b1    = (const float*)d_in[24];
    const float* t_W2    = (const float*)d_in[25];
    const float* t_b2    = (const float*)d_in[26];
    const float* t_ln2g  = (const float*)d_in[27];
    const float* t_ln2b  = (const float*)d_in[28];
    const float* head_W1 = (const float*)d_in[29];
    const float* head_b1 = (const float*)d_in[30];
    const float* head_W2 = (const float*)d_in[31];
    const float* head_b2 = (const float*)d_in[32];

    float* f     = (float*)d_ws;
    float* z32g  = f;                                  // 2M floats
    bf16*  zlastb = (bf16*)(f + (1u << 21));           // 64K bf16
    float* spb   = f + (1u << 21) + 65536;             // 1152 floats
    bf16* BpBase = (bf16*)(f + (1u << 21) + 65536 + 2048);
    bf16* BpSPQKV = BpBase;                            // 147456 bf16
    bf16* BpWS    = BpSPQKV + 147456;                  //  49152
    bf16* BpTQKV  = BpWS + 49152;                      // 147456
    bf16* BpWO    = BpTQKV + 147456;                   //  49152
    bf16* BpW1    = BpWO + 49152;                      // 196608
    bf16* BpW2    = BpW1 + 196608;                     // 196608
    bf16* BpHW1   = BpW2 + 196608;                     //  16384

    RepackArgs ra;
    int s = 0;
    auto mk = [&](int i, const float* W, bf16* out, int K, int N, int ntt, int ntoff, int L) {
        ra.d[i] = {W, out, K, N, ntt, ntoff, L, s};
        s += L * (K >> 5) * (N >> 4) * 64;
    };
    mk(0, sp_Wq, BpSPQKV, 128, 128, 24, 0, 3);
    mk(1, sp_Wk, BpSPQKV, 128, 128, 24, 8, 3);
    mk(2, sp_Wv, BpSPQKV, 128, 128, 24, 16, 3);
    mk(3, sp_Ws, BpWS, 128, 128, 8, 0, 3);
    mk(4, t_Wqkv, BpTQKV, 128, 384, 24, 0, 3);
    mk(5, t_Wo, BpWO, 128, 128, 8, 0, 3);
    mk(6, t_W1, BpW1, 128, 512, 32, 0, 3);
    mk(7, t_W2, BpW2, 512, 128, 8, 0, 3);
    mk(8, head_W1, BpHW1, 128, 128, 8, 0, 1);
    ra.total = s;
    ra.bq = sp_bq; ra.bk = sp_bk; ra.bv = sp_bv; ra.spb = spb;
    k_repack<<<(s + 1152 + 255) / 256, 256, 0, stream>>>(ra);

    k_spatial3<<<BT_, 512, 0, stream>>>(
        input_frames, proj_W, proj_b,
        (const short8*)BpSPQKV, (const short8*)BpWS,
        spb, sp_bs, sp_lng, sp_lnb, edge_attr, sp_We, sp_be, tpos, z32g);

    k_temporal3<<<BN_, 512, 0, stream>>>(
        z32g, (const short8*)BpTQKV, (const short8*)BpWO,
        (const short8*)BpW1, (const short8*)BpW2,
        t_bqkv, t_bo, t_ln1g, t_ln1b, t_b1, t_b2, t_ln2g, t_ln2b, zlastb);

    k_head<<<32, 256, 0, stream>>>(zlastb, (const short8*)BpHW1, head_b1,
                                   head_W2, head_b2, (float*)d_out);
}

// Round 14
// 263.268 us; speedup vs baseline: 1.1119x; 1.0650x over previous
//
#include <hip/hip_runtime.h>
#include <hip/hip_bf16.h>
#include <math.h>

typedef __hip_bfloat16 bf16;
typedef short short8 __attribute__((ext_vector_type(8)));
typedef float floatx4 __attribute__((ext_vector_type(4)));

#define B_    8
#define T_    32
#define N_    64
#define F_    6
#define D_    128
#define E_    4032      // N*(N-1)
#define BT_   256       // B*T
#define BN_   512       // B*N

__device__ __forceinline__ float gelu_exact(float x) {
    return 0.5f * x * (1.0f + erff(x * 0.70710678118654752f));
}
__device__ __forceinline__ float bfbits2f(short s) {
    unsigned int u = ((unsigned int)(unsigned short)s) << 16;
    return __uint_as_float(u);
}
// load 32 consecutive bf16 from LDS (16B-aligned) as fp32
__device__ __forceinline__ void ld32lds(const bf16* p, float* o) {
    const short8* sp = (const short8*)p;
#pragma unroll
    for (int i = 0; i < 4; i++) {
        short8 s = sp[i];
#pragma unroll
        for (int j = 0; j < 8; j++) o[i * 8 + j] = bfbits2f(s[j]);
    }
}

// ---------------------------------------------------------------------------
// Repack weights into MFMA B-fragment layout + pack spatial qkv biases.
struct RepackDesc { const float* W; bf16* out; int K, N, ntt, ntoff, L, start; };
struct RepackArgs {
    RepackDesc d[9]; int total;
    const float *bq, *bk, *bv; float* spb;
};

__global__ void k_repack(RepackArgs ra) {
    int gid = blockIdx.x * blockDim.x + threadIdx.x;
    if (gid >= ra.total) {
        int i = gid - ra.total;
        if (i < 3 * 384) {
            int l = i / 384, c = i % 384;
            float v = (c < 128) ? ra.bq[l * 128 + c]
                    : (c < 256) ? ra.bk[l * 128 + c - 128]
                                : ra.bv[l * 128 + c - 256];
            ra.spb[i] = v;
        }
        return;
    }
    int fi = 0;
    while (fi < 8 && gid >= ra.d[fi + 1].start) fi++;
    RepackDesc dd = ra.d[fi];
    int r = gid - dd.start;
    int lane = r & 63; r >>= 6;
    int ntiles = dd.N >> 4;
    int nt = r % ntiles; r /= ntiles;
    int ktiles = dd.K >> 5;
    int kt = r % ktiles;
    int l = r / ktiles;
    int quad = lane >> 4, cc = lane & 15;
    const float* Wl = dd.W + (size_t)l * dd.K * dd.N;
    bf16* o = dd.out + ((((size_t)l * ktiles + kt) * dd.ntt + nt + dd.ntoff) * 64 + lane) * 8;
    int kb = kt * 32 + quad * 8;
    int n = nt * 16 + cc;
#pragma unroll
    for (int j = 0; j < 8; j++)
        o[j] = __float2bfloat16(Wl[(size_t)(kb + j) * dd.N + n]);
}

// ---------------------------------------------------------------------------
// FUSED 3-layer spatial stack (R13 proven). One block per (b,t) graph,
// 512 thr = 8 waves. Dedicated padded aggf -> 3 barriers/layer.
__global__ __launch_bounds__(512, 1)
void k_spatial3(const float* __restrict__ inp, const float* __restrict__ projW,
                const float* __restrict__ projB,
                const short8* __restrict__ BpQKV, const short8* __restrict__ BpWS,
                const float* __restrict__ spb, const float* __restrict__ bs,
                const float* __restrict__ lng, const float* __restrict__ lnb,
                const float* __restrict__ ea, const float* __restrict__ Weg,
                const float* __restrict__ beg, const float* __restrict__ tpos,
                float* __restrict__ z32g) {
    __shared__ short smem[78208];            // 156416 B
    bf16* hb = (bf16*)smem;                  // [0,8704)s: 64 x 136
    bf16* qk = (bf16*)(smem + 8704);         // 64 x 264 (q|k)
    bf16* Vt = (bf16*)(smem + 25600);        // 128 x 72 (d-major)
    bf16* Ps = (bf16*)(smem + 34816);        // h*4608 + m*72
    float* aggf = (float*)(smem + 53248);    // 64 x 132 fp32 (dedicated)
    float* fsm = aggf;                       // proj staging overlay
    float* EAs = (float*)(smem + 70144);     // 4032 fp32

    int bt = blockIdx.x;
    int tid = threadIdx.x;
    int lane = tid & 63, w = tid >> 6;
    int quad = lane >> 4, col = lane & 15;
    int w4 = w & 3, wh = w >> 2;
    const float scale = 0.17677669529663687f;   // 1/sqrt(32)

    for (int i = tid; i < 896; i += 512)
        fsm[i] = (i < 768) ? projW[i] : projB[i - 768];
    {
        const float* eag = ea + (size_t)bt * E_;
        for (int i = tid; i < E_; i += 512) EAs[i] = eag[i];
    }
    __syncthreads();
    float hreg[32];
    if (w < 4) {
#pragma unroll
        for (int r = 0; r < 4; r++) {
            int n = w * 16 + quad * 4 + r;
            const float* xr = inp + (size_t)(bt * 64 + n) * F_;
            float xin[6];
#pragma unroll
            for (int k2 = 0; k2 < 6; k2++) xin[k2] = xr[k2];
#pragma unroll
            for (int tt = 0; tt < 8; tt++) {
                int c = tt * 16 + col;
                float a = fsm[768 + c];
#pragma unroll
                for (int k2 = 0; k2 < 6; k2++) a = fmaf(xin[k2], fsm[k2 * 128 + c], a);
                hreg[tt * 4 + r] = a;
                hb[n * 136 + c] = __float2bfloat16(a);
            }
        }
    }
    __syncthreads();                         // B0

    for (int l = 0; l < 3; l++) {
        // ---- phase 1: qkv GEMM ----
        {
            floatx4 acc[12];
#pragma unroll
            for (int tt = 0; tt < 12; tt++) acc[tt] = (floatx4){0.f, 0.f, 0.f, 0.f};
            const short8* bpl = BpQKV + (size_t)l * 6144;
            for (int kt = 0; kt < 4; kt++) {
                short8 a = *(const short8*)&hb[(w4 * 16 + col) * 136 + kt * 32 + quad * 8];
                const short8* bp = bpl + (size_t)(kt * 24 + wh * 12) * 64 + lane;
#pragma unroll
                for (int tt = 0; tt < 12; tt++)
                    acc[tt] = __builtin_amdgcn_mfma_f32_16x16x32_bf16(a, bp[tt * 64], acc[tt], 0, 0, 0);
            }
            const float* bias = spb + l * 384;
#pragma unroll
            for (int tt = 0; tt < 12; tt++) {
                int c = wh * 192 + tt * 16 + col;
                float bv = bias[c];
#pragma unroll
                for (int r = 0; r < 4; r++) {
                    int row = w4 * 16 + quad * 4 + r;
                    bf16 v = __float2bfloat16(acc[tt][r] + bv);
                    if (c < 256) qk[row * 264 + c] = v;
                    else         Vt[(c - 256) * 72 + row] = v;
                }
            }
        }
        __syncthreads();                     // B1: qk/Vt visible
        // ---- phase 2: attention (no barrier until aggf done) ----
        int h = w4, half = wh;
        int hoff = h * 32;
        const float* Wel = Weg + l * 128 + hoff;
        const float* bel = beg + l * 128 + hoff;
        float qWe;
        {
            int dst = half * 32 + (lane & 31);
            float qr[32];
            ld32lds(&qk[dst * 264 + hoff], qr);
            float s0 = 0.f, s1 = 0.f, s2 = 0.f, s3 = 0.f;
#pragma unroll
            for (int c2 = 0; c2 < 32; c2 += 4) {
                s0 = fmaf(qr[c2], Wel[c2], s0);
                s1 = fmaf(qr[c2 + 1], Wel[c2 + 1], s1);
                s2 = fmaf(qr[c2 + 2], Wel[c2 + 2], s2);
                s3 = fmaf(qr[c2 + 3], Wel[c2 + 3], s3);
            }
            qWe = (s0 + s1) + (s2 + s3);
        }
        float s[2][4][4], ev[2][4][4];
        {
            short8 aA[2], bB[4];
#pragma unroll
            for (int mtl = 0; mtl < 2; mtl++)
                aA[mtl] = *(const short8*)&qk[((half * 2 + mtl) * 16 + col) * 264 + hoff + quad * 8];
#pragma unroll
            for (int nt = 0; nt < 4; nt++)
                bB[nt] = *(const short8*)&qk[(nt * 16 + col) * 264 + 128 + hoff + quad * 8];
#pragma unroll
            for (int mtl = 0; mtl < 2; mtl++)
#pragma unroll
                for (int nt = 0; nt < 4; nt++) {
                    floatx4 acc = (floatx4){0.f, 0.f, 0.f, 0.f};
                    acc = __builtin_amdgcn_mfma_f32_16x16x32_bf16(aA[mtl], bB[nt], acc, 0, 0, 0);
#pragma unroll
                    for (int r = 0; r < 4; r++) s[mtl][nt][r] = acc[r];
                }
        }
        float ls[2][4], ae[2][4], inv[2][4];
#pragma unroll
        for (int mtl = 0; mtl < 2; mtl++)
#pragma unroll
            for (int r = 0; r < 4; r++) {
                int m = half * 32 + mtl * 16 + quad * 4 + r;
                float qWeR = __shfl(qWe, mtl * 16 + quad * 4 + r, 64);
                float rmax = -1e30f;
#pragma unroll
                for (int nt = 0; nt < 4; nt++) {
                    int n = nt * 16 + col;
                    bool diag = (m == n);
                    int eid = diag ? 0 : (n * 63 + m - (m > n ? 1 : 0));
                    float eav = diag ? 0.f : EAs[eid];
                    ev[mtl][nt][r] = eav;
                    float al = diag ? -1e30f
                                    : scale * (s[mtl][nt][r] + eav * qWeR);
                    s[mtl][nt][r] = al;
                    rmax = fmaxf(rmax, al);
                }
#pragma unroll
                for (int mk2 = 1; mk2 <= 8; mk2 <<= 1)
                    rmax = fmaxf(rmax, __shfl_xor(rmax, mk2, 64));
                float lsum = 0.f, aesum = 0.f;
#pragma unroll
                for (int nt = 0; nt < 4; nt++) {
                    float p = __expf(s[mtl][nt][r] - rmax);
                    s[mtl][nt][r] = p;
                    lsum += p;
                    aesum = fmaf(p, ev[mtl][nt][r], aesum);
                }
#pragma unroll
                for (int mk2 = 1; mk2 <= 8; mk2 <<= 1) {
                    lsum += __shfl_xor(lsum, mk2, 64);
                    aesum += __shfl_xor(aesum, mk2, 64);
                }
                ls[mtl][r] = lsum;
                ae[mtl][r] = aesum;
                inv[mtl][r] = 1.0f / lsum;
            }
        // PV: P hi/lo compensated bf16 split (Ps wave-private)
        bf16* PsH = Ps + h * 4608;
        floatx4 oacc[2][2];
#pragma unroll
        for (int mtl = 0; mtl < 2; mtl++)
#pragma unroll
            for (int ntB = 0; ntB < 2; ntB++) oacc[mtl][ntB] = (floatx4){0.f, 0.f, 0.f, 0.f};
#pragma unroll
        for (int p = 0; p < 2; p++) {
#pragma unroll
            for (int mtl = 0; mtl < 2; mtl++)
#pragma unroll
                for (int q2 = 0; q2 < 2; q2++) {
                    int nl = q2 * 16 + col;
                    int base0 = (half * 32 + mtl * 16 + quad * 4) * 72 + ((nl >> 3) * 2) * 8 + (nl & 7);
#pragma unroll
                    for (int r = 0; r < 4; r++) {
                        float p_ = s[mtl][2 * p + q2][r];
                        bf16 hi = __float2bfloat16(p_);
                        bf16 lo = __float2bfloat16(p_ - bfbits2f(*(short*)&hi));
                        PsH[base0 + r * 72] = hi;
                        PsH[base0 + r * 72 + 8] = lo;
                    }
                }
            short8 aPh[2], aPl[2], bV[2];
#pragma unroll
            for (int mtl = 0; mtl < 2; mtl++) {
                int rb = (half * 32 + mtl * 16 + col) * 72 + quad * 16;
                aPh[mtl] = *(const short8*)&PsH[rb];
                aPl[mtl] = *(const short8*)&PsH[rb + 8];
            }
#pragma unroll
            for (int ntB = 0; ntB < 2; ntB++)
                bV[ntB] = *(const short8*)&Vt[(hoff + ntB * 16 + col) * 72 + p * 32 + quad * 8];
#pragma unroll
            for (int mtl = 0; mtl < 2; mtl++)
#pragma unroll
                for (int ntB = 0; ntB < 2; ntB++) {
                    oacc[mtl][ntB] = __builtin_amdgcn_mfma_f32_16x16x32_bf16(aPh[mtl], bV[ntB], oacc[mtl][ntB], 0, 0, 0);
                    oacc[mtl][ntB] = __builtin_amdgcn_mfma_f32_16x16x32_bf16(aPl[mtl], bV[ntB], oacc[mtl][ntB], 0, 0, 0);
                }
        }
#pragma unroll
        for (int mtl = 0; mtl < 2; mtl++)
#pragma unroll
            for (int ntB = 0; ntB < 2; ntB++) {
                int c = hoff + ntB * 16 + col;
                float Wc = Wel[ntB * 16 + col];
                float bc = bel[ntB * 16 + col];
#pragma unroll
                for (int r = 0; r < 4; r++) {
                    int m = half * 32 + mtl * 16 + quad * 4 + r;
                    aggf[m * 132 + c] = fmaf(fmaf(ae[mtl][r], Wc, oacc[mtl][ntB][r]),
                                             inv[mtl][r], bc);
                }
            }
        __syncthreads();                     // B2: agg visible (qk reads also done)
        // ---- epilogue: Ws GEMM + agg + residual + LN (waves 0-3) ----
        if (w < 4) {
            floatx4 acc2[8];
#pragma unroll
            for (int tt = 0; tt < 8; tt++) acc2[tt] = (floatx4){0.f, 0.f, 0.f, 0.f};
            const short8* bpl = BpWS + (size_t)l * 2048;
            for (int kt = 0; kt < 4; kt++) {
                short8 a = *(const short8*)&hb[(w * 16 + col) * 136 + kt * 32 + quad * 8];
                const short8* bp = bpl + (size_t)(kt * 8) * 64 + lane;
#pragma unroll
                for (int tt = 0; tt < 8; tt++)
                    acc2[tt] = __builtin_amdgcn_mfma_f32_16x16x32_bf16(a, bp[tt * 64], acc2[tt], 0, 0, 0);
            }
            const float* bsl = bs + l * 128;
            float vv[32], rs[4] = {0.f, 0.f, 0.f, 0.f};
#pragma unroll
            for (int tt = 0; tt < 8; tt++) {
                int c = tt * 16 + col;
                float bv = bsl[c];
#pragma unroll
                for (int r = 0; r < 4; r++) {
                    int row = w * 16 + quad * 4 + r;
                    float v = acc2[tt][r] + bv + aggf[row * 132 + c] + hreg[tt * 4 + r];
                    vv[tt * 4 + r] = v;
                    rs[r] += v;
                }
            }
#pragma unroll
            for (int m = 1; m <= 8; m <<= 1)
#pragma unroll
                for (int r = 0; r < 4; r++) rs[r] += __shfl_xor(rs[r], m, 64);
            float mean[4], vs[4] = {0.f, 0.f, 0.f, 0.f};
#pragma unroll
            for (int r = 0; r < 4; r++) mean[r] = rs[r] * (1.0f / 128.0f);
#pragma unroll
            for (int i = 0; i < 32; i++) {
                float d = vv[i] - mean[i & 3];
                vv[i] = d;
                vs[i & 3] += d * d;
            }
#pragma unroll
            for (int m = 1; m <= 8; m <<= 1)
#pragma unroll
                for (int r = 0; r < 4; r++) vs[r] += __shfl_xor(vs[r], m, 64);
            float inv2[4];
#pragma unroll
            for (int r = 0; r < 4; r++) inv2[r] = rsqrtf(vs[r] * (1.0f / 128.0f) + 1e-5f);
            const float* gl = lng + l * 128;
            const float* bl = lnb + l * 128;
            if (l < 2) {
#pragma unroll
                for (int tt = 0; tt < 8; tt++) {
                    int c = tt * 16 + col;
                    float gc = gl[c], bc = bl[c];
#pragma unroll
                    for (int r = 0; r < 4; r++) {
                        float y = vv[tt * 4 + r] * inv2[r] * gc + bc;
                        int n = w * 16 + quad * 4 + r;
                        hreg[tt * 4 + r] = y;
                        hb[n * 136 + c] = __float2bfloat16(y);
                    }
                }
            } else {
                int b = bt >> 5, t_ = bt & 31;
#pragma unroll
                for (int tt = 0; tt < 8; tt++) {
                    int c = tt * 16 + col;
                    float gc = gl[c], bc = bl[c], pc = tpos[t_ * 128 + c];
#pragma unroll
                    for (int r = 0; r < 4; r++) {
                        float y = vv[tt * 4 + r] * inv2[r] * gc + bc;
                        int n = w * 16 + quad * 4 + r;
                        z32g[((size_t)(b * 64 + n) * 32 + t_) * 128 + c] = y + pc;
                    }
                }
            }
        }
        __syncthreads();                     // B3: layer complete
    }
}

// ---------------------------------------------------------------------------
// FUSED 3-layer temporal stack. R11/R13 structure + software-pipelined
// B-fragment loads (2-deep kt double-buffer) in qkv/Wo/W1/W2 phases to break
// in-phase L2-load serialization (VGPR 64 -> target ~100-128, cap 128).
__global__ __launch_bounds__(512, 4)
void k_temporal3(const float* __restrict__ z32g,
                 const short8* __restrict__ BpQKV, const short8* __restrict__ BpWO,
                 const short8* __restrict__ BpW1, const short8* __restrict__ BpW2,
                 const float* __restrict__ bqkv, const float* __restrict__ bo,
                 const float* __restrict__ ln1g, const float* __restrict__ ln1b,
                 const float* __restrict__ b1, const float* __restrict__ b2,
                 const float* __restrict__ ln2g, const float* __restrict__ ln2b,
                 bf16* __restrict__ zlastb) {
    __shared__ short smem[32000];            // 64000 B
    bf16* zb  = (bf16*)smem;                 // [0,4352)s: 32 x 136
    bf16* qk  = (bf16*)(smem + 4352);        // 32 x 264
    bf16* Ps  = (bf16*)(smem + 12800);       // (h*2+mh)*1152
    bf16* Vt  = (bf16*)(smem + 22016);       // d*40 + t
    bf16* o16 = (bf16*)(smem + 27136);       // 32 x 136
    float* lnp = (float*)(smem + 31488);     // 4x32x2 fp32
    bf16* f1  = (bf16*)(smem + 4352);        // overlay: 32 x 520

    int bn = blockIdx.x;
    int tid = threadIdx.x;
    int lane = tid & 63, w = tid >> 6;
    int quad = lane >> 4, col = lane & 15;
    int mt = w & 1, cq = w >> 1;
    const float scale = 0.17677669529663687f;

    for (int i = tid; i < 4096; i += 512) {
        float v = z32g[(size_t)bn * 4096 + i];
        zb[(i >> 7) * 136 + (i & 127)] = __float2bfloat16(v);
    }
    float zreg[8];
#pragma unroll
    for (int t2 = 0; t2 < 2; t2++)
#pragma unroll
        for (int r = 0; r < 4; r++)
            zreg[t2 * 4 + r] = z32g[(size_t)bn * 4096 +
                                    (mt * 16 + quad * 4 + r) * 128 + cq * 32 + t2 * 16 + col];
    __syncthreads();

    for (int l = 0; l < 3; l++) {
        // ---- phase 1: qkv GEMM (pipelined B loads) ----
        {
            floatx4 acc[6];
#pragma unroll
            for (int tt = 0; tt < 6; tt++) acc[tt] = (floatx4){0.f, 0.f, 0.f, 0.f};
            const short8* bpl = BpQKV + (size_t)l * 6144 + (size_t)(cq * 6) * 64 + lane;
            short8 bb[2][6];
#pragma unroll
            for (int tt = 0; tt < 6; tt++) bb[0][tt] = bpl[tt * 64];
#pragma unroll
            for (int kt = 0; kt < 4; kt++) {
                int cur = kt & 1;
                if (kt < 3) {
                    const short8* bpn = bpl + (size_t)((kt + 1) * 24) * 64;
#pragma unroll
                    for (int tt = 0; tt < 6; tt++) bb[cur ^ 1][tt] = bpn[tt * 64];
                }
                short8 a = *(const short8*)&zb[(mt * 16 + col) * 136 + kt * 32 + quad * 8];
#pragma unroll
                for (int tt = 0; tt < 6; tt++)
                    acc[tt] = __builtin_amdgcn_mfma_f32_16x16x32_bf16(a, bb[cur][tt], acc[tt], 0, 0, 0);
            }
            const float* bias = bqkv + l * 384;
#pragma unroll
            for (int tt = 0; tt < 6; tt++) {
                int c = cq * 96 + tt * 16 + col;
                float bv = bias[c];
#pragma unroll
                for (int r = 0; r < 4; r++) {
                    int row = mt * 16 + quad * 4 + r;
                    bf16 v = __float2bfloat16(acc[tt][r] + bv);
                    if (c < 256) qk[row * 264 + c] = v;
                    else         Vt[(c - 256) * 40 + row] = v;
                }
            }
        }
        __syncthreads();                     // B1
        // ---- phase 2: attention. wave=(h=w&3, mh=w>>2) ----
        {
            int h = w & 3, mh = w >> 2;
            int hoff = h * 32;
            bf16* PsH = Ps + (h * 2 + mh) * 1152;
            float s[2][4];
            short8 aA = *(const short8*)&qk[(mh * 16 + col) * 264 + hoff + quad * 8];
            short8 bB[2];
#pragma unroll
            for (int nt = 0; nt < 2; nt++)
                bB[nt] = *(const short8*)&qk[(nt * 16 + col) * 264 + 128 + hoff + quad * 8];
#pragma unroll
            for (int nt = 0; nt < 2; nt++) {
                floatx4 acc = (floatx4){0.f, 0.f, 0.f, 0.f};
                acc = __builtin_amdgcn_mfma_f32_16x16x32_bf16(aA, bB[nt], acc, 0, 0, 0);
#pragma unroll
                for (int r = 0; r < 4; r++) s[nt][r] = acc[r];
            }
            float inv[4];
#pragma unroll
            for (int r = 0; r < 4; r++) {
                int m = mh * 16 + quad * 4 + r;
                float rmax = -1e30f;
#pragma unroll
                for (int nt = 0; nt < 2; nt++) {
                    int n = nt * 16 + col;
                    float al = (n > m) ? -1e30f : s[nt][r] * scale;
                    s[nt][r] = al;
                    rmax = fmaxf(rmax, al);
                }
#pragma unroll
                for (int mk2 = 1; mk2 <= 8; mk2 <<= 1)
                    rmax = fmaxf(rmax, __shfl_xor(rmax, mk2, 64));
                float lsum = 0.f;
#pragma unroll
                for (int nt = 0; nt < 2; nt++) {
                    float p = __expf(s[nt][r] - rmax);
                    s[nt][r] = p;
                    lsum += p;
                }
#pragma unroll
                for (int mk2 = 1; mk2 <= 8; mk2 <<= 1)
                    lsum += __shfl_xor(lsum, mk2, 64);
                inv[r] = 1.0f / lsum;
            }
#pragma unroll
            for (int nt = 0; nt < 2; nt++) {
                int n = nt * 16 + col;
                int base0 = (quad * 4) * 72 + ((n >> 3) * 2) * 8 + (n & 7);
#pragma unroll
                for (int r = 0; r < 4; r++) {
                    float p_ = s[nt][r];
                    bf16 hi = __float2bfloat16(p_);
                    bf16 lo = __float2bfloat16(p_ - bfbits2f(*(short*)&hi));
                    PsH[base0 + r * 72] = hi;
                    PsH[base0 + r * 72 + 8] = lo;
                }
            }
            floatx4 oacc[2];
#pragma unroll
            for (int nt = 0; nt < 2; nt++) oacc[nt] = (floatx4){0.f, 0.f, 0.f, 0.f};
            short8 aPh = *(const short8*)&PsH[col * 72 + quad * 16];
            short8 aPl = *(const short8*)&PsH[col * 72 + quad * 16 + 8];
            short8 bV[2];
#pragma unroll
            for (int nt = 0; nt < 2; nt++)
                bV[nt] = *(const short8*)&Vt[(hoff + nt * 16 + col) * 40 + quad * 8];
#pragma unroll
            for (int nt = 0; nt < 2; nt++) {
                oacc[nt] = __builtin_amdgcn_mfma_f32_16x16x32_bf16(aPh, bV[nt], oacc[nt], 0, 0, 0);
                oacc[nt] = __builtin_amdgcn_mfma_f32_16x16x32_bf16(aPl, bV[nt], oacc[nt], 0, 0, 0);
            }
#pragma unroll
            for (int nt = 0; nt < 2; nt++) {
                int c = hoff + nt * 16 + col;
#pragma unroll
                for (int r = 0; r < 4; r++)
                    o16[(mh * 16 + quad * 4 + r) * 136 + c] =
                        __float2bfloat16(oacc[nt][r] * inv[r]);
            }
        }
        __syncthreads();                     // B2
        // ---- Wo GEMM + residual + LN1 (pipelined B loads) ----
        {
            floatx4 acc2[2];
#pragma unroll
            for (int tt = 0; tt < 2; tt++) acc2[tt] = (floatx4){0.f, 0.f, 0.f, 0.f};
            const short8* bpl = BpWO + (size_t)l * 2048 + (size_t)(cq * 2) * 64 + lane;
            short8 bb[2][2];
#pragma unroll
            for (int tt = 0; tt < 2; tt++) bb[0][tt] = bpl[tt * 64];
#pragma unroll
            for (int kt = 0; kt < 4; kt++) {
                int cur = kt & 1;
                if (kt < 3) {
                    const short8* bpn = bpl + (size_t)((kt + 1) * 8) * 64;
#pragma unroll
                    for (int tt = 0; tt < 2; tt++) bb[cur ^ 1][tt] = bpn[tt * 64];
                }
                short8 a = *(const short8*)&o16[(mt * 16 + col) * 136 + kt * 32 + quad * 8];
#pragma unroll
                for (int tt = 0; tt < 2; tt++)
                    acc2[tt] = __builtin_amdgcn_mfma_f32_16x16x32_bf16(a, bb[cur][tt], acc2[tt], 0, 0, 0);
            }
            const float* bol = bo + l * 128;
            float vv[8], rs[4] = {0.f, 0.f, 0.f, 0.f}, rq[4] = {0.f, 0.f, 0.f, 0.f};
#pragma unroll
            for (int tt = 0; tt < 2; tt++) {
                int c = cq * 32 + tt * 16 + col;
                float bv = bol[c];
#pragma unroll
                for (int r = 0; r < 4; r++) {
                    float v = acc2[tt][r] + bv + zreg[tt * 4 + r];
                    vv[tt * 4 + r] = v;
                    rs[r] += v;
                    rq[r] = fmaf(v, v, rq[r]);
                }
            }
#pragma unroll
            for (int m = 1; m <= 8; m <<= 1)
#pragma unroll
                for (int r = 0; r < 4; r++) {
                    rs[r] += __shfl_xor(rs[r], m, 64);
                    rq[r] += __shfl_xor(rq[r], m, 64);
                }
            if (col == 0) {
#pragma unroll
                for (int r = 0; r < 4; r++) {
                    int row = mt * 16 + quad * 4 + r;
                    lnp[(cq * 32 + row) * 2] = rs[r];
                    lnp[(cq * 32 + row) * 2 + 1] = rq[r];
                }
            }
            __syncthreads();                 // B3
            const float* gl = ln1g + l * 128;
            const float* bl = ln1b + l * 128;
#pragma unroll
            for (int r = 0; r < 4; r++) {
                int row = mt * 16 + quad * 4 + r;
                float sm = 0.f, sq = 0.f;
#pragma unroll
                for (int q2 = 0; q2 < 4; q2++) {
                    sm += lnp[(q2 * 32 + row) * 2];
                    sq += lnp[(q2 * 32 + row) * 2 + 1];
                }
                float mean = sm * (1.0f / 128.0f);
                float var = sq * (1.0f / 128.0f) - mean * mean;
                float iv = rsqrtf(var + 1e-5f);
#pragma unroll
                for (int tt = 0; tt < 2; tt++) {
                    int c = cq * 32 + tt * 16 + col;
                    float y = (vv[tt * 4 + r] - mean) * iv * gl[c] + bl[c];
                    zreg[tt * 4 + r] = y;
                    zb[row * 136 + c] = __float2bfloat16(y);
                }
            }
        }
        __syncthreads();                     // B4
        // ---- W1 GEMM + gelu (pipelined B loads) ----
        {
            floatx4 acc3[8];
#pragma unroll
            for (int tt = 0; tt < 8; tt++) acc3[tt] = (floatx4){0.f, 0.f, 0.f, 0.f};
            const short8* bpl = BpW1 + (size_t)l * 8192 + (size_t)(cq * 8) * 64 + lane;
            short8 bb[2][8];
#pragma unroll
            for (int tt = 0; tt < 8; tt++) bb[0][tt] = bpl[tt * 64];
#pragma unroll
            for (int kt = 0; kt < 4; kt++) {
                int cur = kt & 1;
                if (kt < 3) {
                    const short8* bpn = bpl + (size_t)((kt + 1) * 32) * 64;
#pragma unroll
                    for (int tt = 0; tt < 8; tt++) bb[cur ^ 1][tt] = bpn[tt * 64];
                }
                short8 a = *(const short8*)&zb[(mt * 16 + col) * 136 + kt * 32 + quad * 8];
#pragma unroll
                for (int tt = 0; tt < 8; tt++)
                    acc3[tt] = __builtin_amdgcn_mfma_f32_16x16x32_bf16(a, bb[cur][tt], acc3[tt], 0, 0, 0);
            }
            const float* b1l = b1 + l * 512;
#pragma unroll
            for (int tt = 0; tt < 8; tt++) {
                int c = cq * 128 + tt * 16 + col;
                float bv = b1l[c];
#pragma unroll
                for (int r = 0; r < 4; r++) {
                    float v = gelu_exact(acc3[tt][r] + bv);
                    f1[(mt * 16 + quad * 4 + r) * 520 + c] = __float2bfloat16(v);
                }
            }
        }
        __syncthreads();                     // B5
        // ---- W2 GEMM + residual + LN2 (pipelined B loads, K=512) ----
        {
            floatx4 acc4[2];
#pragma unroll
            for (int tt = 0; tt < 2; tt++) acc4[tt] = (floatx4){0.f, 0.f, 0.f, 0.f};
            const short8* bpl = BpW2 + (size_t)l * 8192 + (size_t)(cq * 2) * 64 + lane;
            short8 bb[2][2];
#pragma unroll
            for (int tt = 0; tt < 2; tt++) bb[0][tt] = bpl[tt * 64];
#pragma unroll
            for (int kt = 0; kt < 16; kt++) {
                int cur = kt & 1;
                if (kt < 15) {
                    const short8* bpn = bpl + (size_t)((kt + 1) * 8) * 64;
#pragma unroll
                    for (int tt = 0; tt < 2; tt++) bb[cur ^ 1][tt] = bpn[tt * 64];
                }
                short8 a = *(const short8*)&f1[(mt * 16 + col) * 520 + kt * 32 + quad * 8];
#pragma unroll
                for (int tt = 0; tt < 2; tt++)
                    acc4[tt] = __builtin_amdgcn_mfma_f32_16x16x32_bf16(a, bb[cur][tt], acc4[tt], 0, 0, 0);
            }
            const float* b2l = b2 + l * 128;
            float vv[8], rs[4] = {0.f, 0.f, 0.f, 0.f}, rq[4] = {0.f, 0.f, 0.f, 0.f};
#pragma unroll
            for (int tt = 0; tt < 2; tt++) {
                int c = cq * 32 + tt * 16 + col;
                float bv = b2l[c];
#pragma unroll
                for (int r = 0; r < 4; r++) {
                    float v = acc4[tt][r] + bv + zreg[tt * 4 + r];
                    vv[tt * 4 + r] = v;
                    rs[r] += v;
                    rq[r] = fmaf(v, v, rq[r]);
                }
            }
#pragma unroll
            for (int m = 1; m <= 8; m <<= 1)
#pragma unroll
                for (int r = 0; r < 4; r++) {
                    rs[r] += __shfl_xor(rs[r], m, 64);
                    rq[r] += __shfl_xor(rq[r], m, 64);
                }
            if (col == 0) {
#pragma unroll
                for (int r = 0; r < 4; r++) {
                    int row = mt * 16 + quad * 4 + r;
                    lnp[(cq * 32 + row) * 2] = rs[r];
                    lnp[(cq * 32 + row) * 2 + 1] = rq[r];
                }
            }
            __syncthreads();                 // B6
            const float* gl = ln2g + l * 128;
            const float* bl = ln2b + l * 128;
#pragma unroll
            for (int r = 0; r < 4; r++) {
                int row = mt * 16 + quad * 4 + r;
                float sm = 0.f, sq = 0.f;
#pragma unroll
                for (int q2 = 0; q2 < 4; q2++) {
                    sm += lnp[(q2 * 32 + row) * 2];
                    sq += lnp[(q2 * 32 + row) * 2 + 1];
                }
                float mean = sm * (1.0f / 128.0f);
                float var = sq * (1.0f / 128.0f) - mean * mean;
                float iv = rsqrtf(var + 1e-5f);
#pragma unroll
                for (int tt = 0; tt < 2; tt++) {
                    int c = cq * 32 + tt * 16 + col;
                    float y = (vv[tt * 4 + r] - mean) * iv * gl[c] + bl[c];
                    zreg[tt * 4 + r] = y;
                    if (l < 2) zb[row * 136 + c] = __float2bfloat16(y);
                    else if (row == 31) zlastb[(size_t)bn * 128 + c] = __float2bfloat16(y);
                }
            }
        }
        __syncthreads();                     // B7
    }
}

// ---------------------------------------------------------------------------
// Head (MFMA): out = gelu(zlast @ W1 + b1) @ W2 + b2. Grid 32 x 256 thr.
__global__ __launch_bounds__(256)
void k_head(const bf16* __restrict__ zlastb, const short8* __restrict__ BpHW1,
            const float* __restrict__ b1, const float* __restrict__ W2,
            const float* __restrict__ b2, float* __restrict__ out) {
    __shared__ bf16 h1[16 * 136];
    int blk = blockIdx.x;
    int tid = threadIdx.x;
    int lane = tid & 63, w = tid >> 6;
    int quad = lane >> 4, col = lane & 15;
    {
        floatx4 acc[2];
        acc[0] = (floatx4){0.f, 0.f, 0.f, 0.f};
        acc[1] = (floatx4){0.f, 0.f, 0.f, 0.f};
        const short8* Ap = (const short8*)(zlastb + (size_t)(blk * 16 + col) * 128) + quad;
        for (int kt = 0; kt < 4; kt++) {
            short8 a = Ap[kt * 4];
            const short8* bp = BpHW1 + (size_t)(kt * 8 + w * 2) * 64 + lane;
            acc[0] = __builtin_amdgcn_mfma_f32_16x16x32_bf16(a, bp[0], acc[0], 0, 0, 0);
            acc[1] = __builtin_amdgcn_mfma_f32_16x16x32_bf16(a, bp[64], acc[1], 0, 0, 0);
        }
#pragma unroll
        for (int tt = 0; tt < 2; tt++) {
            int c = w * 32 + tt * 16 + col;
            float bv = b1[c];
#pragma unroll
            for (int r = 0; r < 4; r++)
                h1[(quad * 4 + r) * 136 + c] = __float2bfloat16(gelu_exact(acc[tt][r] + bv));
        }
    }
    __syncthreads();
    if (tid < 96) {
        int row = tid / 6, c = tid % 6;
        float a0 = 0.f, a1 = 0.f, a2 = 0.f, a3 = 0.f;
        const bf16* hr = &h1[row * 136];
#pragma unroll 8
        for (int k = 0; k < 128; k += 4) {
            a0 = fmaf(bfbits2f(*(const short*)&hr[k]),     W2[k * 6 + c], a0);
            a1 = fmaf(bfbits2f(*(const short*)&hr[k + 1]), W2[(k + 1) * 6 + c], a1);
            a2 = fmaf(bfbits2f(*(const short*)&hr[k + 2]), W2[(k + 2) * 6 + c], a2);
            a3 = fmaf(bfbits2f(*(const short*)&hr[k + 3]), W2[(k + 3) * 6 + c], a3);
        }
        out[(size_t)(blk * 16 + row) * 6 + c] = (a0 + a1) + (a2 + a3) + b2[c];
    }
}

// ---------------------------------------------------------------------------
extern "C" void kernel_launch(void* const* d_in, const int* in_sizes, int n_in,
                              void* d_out, int out_size, void* d_ws, size_t ws_size,
                              hipStream_t stream) {
    const float* input_frames = (const float*)d_in[0];
    const float* edge_attr    = (const float*)d_in[1];
    const float* proj_W  = (const float*)d_in[2];
    const float* proj_b  = (const float*)d_in[3];
    const float* sp_Wq   = (const float*)d_in[4];
    const float* sp_bq   = (const float*)d_in[5];
    const float* sp_Wk   = (const float*)d_in[6];
    const float* sp_bk   = (const float*)d_in[7];
    const float* sp_Wv   = (const float*)d_in[8];
    const float* sp_bv   = (const float*)d_in[9];
    const float* sp_We   = (const float*)d_in[10];
    const float* sp_be   = (const float*)d_in[11];
    const float* sp_Ws   = (const float*)d_in[12];
    const float* sp_bs   = (const float*)d_in[13];
    const float* sp_lng  = (const float*)d_in[14];
    const float* sp_lnb  = (const float*)d_in[15];
    const float* tpos    = (const float*)d_in[16];
    const float* t_Wqkv  = (const float*)d_in[17];
    const float* t_bqkv  = (const float*)d_in[18];
    const float* t_Wo    = (const float*)d_in[19];
    const float* t_bo    = (const float*)d_in[20];
    const float* t_ln1g  = (const float*)d_in[21];
    const float* t_ln1b  = (const float*)d_in[22];
    const float* t_W1    = (const float*)d_in[23];
    const float* t_b1    = (const float*)d_in[24];
    const float* t_W2    = (const float*)d_in[25];
    const float* t_b2    = (const float*)d_in[26];
    const float* t_ln2g  = (const float*)d_in[27];
    const float* t_ln2b  = (const float*)d_in[28];
    const float* head_W1 = (const float*)d_in[29];
    const float* head_b1 = (const float*)d_in[30];
    const float* head_W2 = (const float*)d_in[31];
    const float* head_b2 = (const float*)d_in[32];

    float* f     = (float*)d_ws;
    float* z32g  = f;                                  // 2M floats
    bf16*  zlastb = (bf16*)(f + (1u << 21));           // 64K bf16
    float* spb   = f + (1u << 21) + 65536;             // 1152 floats
    bf16* BpBase = (bf16*)(f + (1u << 21) + 65536 + 2048);
    bf16* BpSPQKV = BpBase;                            // 147456 bf16
    bf16* BpWS    = BpSPQKV + 147456;                  //  49152
    bf16* BpTQKV  = BpWS + 49152;                      // 147456
    bf16* BpWO    = BpTQKV + 147456;                   //  49152
    bf16* BpW1    = BpWO + 49152;                      // 196608
    bf16* BpW2    = BpW1 + 196608;                     // 196608
    bf16* BpHW1   = BpW2 + 196608;                     //  16384

    RepackArgs ra;
    int s = 0;
    auto mk = [&](int i, const float* W, bf16* out, int K, int N, int ntt, int ntoff, int L) {
        ra.d[i] = {W, out, K, N, ntt, ntoff, L, s};
        s += L * (K >> 5) * (N >> 4) * 64;
    };
    mk(0, sp_Wq, BpSPQKV, 128, 128, 24, 0, 3);
    mk(1, sp_Wk, BpSPQKV, 128, 128, 24, 8, 3);
    mk(2, sp_Wv, BpSPQKV, 128, 128, 24, 16, 3);
    mk(3, sp_Ws, BpWS, 128, 128, 8, 0, 3);
    mk(4, t_Wqkv, BpTQKV, 128, 384, 24, 0, 3);
    mk(5, t_Wo, BpWO, 128, 128, 8, 0, 3);
    mk(6, t_W1, BpW1, 128, 512, 32, 0, 3);
    mk(7, t_W2, BpW2, 512, 128, 8, 0, 3);
    mk(8, head_W1, BpHW1, 128, 128, 8, 0, 1);
    ra.total = s;
    ra.bq = sp_bq; ra.bk = sp_bk; ra.bv = sp_bv; ra.spb = spb;
    k_repack<<<(s + 1152 + 255) / 256, 256, 0, stream>>>(ra);

    k_spatial3<<<BT_, 512, 0, stream>>>(
        input_frames, proj_W, proj_b,
        (const short8*)BpSPQKV, (const short8*)BpWS,
        spb, sp_bs, sp_lng, sp_lnb, edge_attr, sp_We, sp_be, tpos, z32g);

    k_temporal3<<<BN_, 512, 0, stream>>>(
        z32g, (const short8*)BpTQKV, (const short8*)BpWO,
        (const short8*)BpW1, (const short8*)BpW2,
        t_bqkv, t_bo, t_ln1g, t_ln1b, t_b1, t_b2, t_ln2g, t_ln2b, zlastb);

    k_head<<<32, 256, 0, stream>>>(zlastb, (const short8*)BpHW1, head_b1,
                                   head_W2, head_b2, (float*)d_out);
}

// Round 15
// 262.323 us; speedup vs baseline: 1.1159x; 1.0036x over previous
//
#include <hip/hip_runtime.h>
#include <hip/hip_bf16.h>
#include <math.h>

typedef __hip_bfloat16 bf16;
typedef short short8 __attribute__((ext_vector_type(8)));
typedef float floatx4 __attribute__((ext_vector_type(4)));

#define B_    8
#define T_    32
#define N_    64
#define F_    6
#define D_    128
#define E_    4032      // N*(N-1)
#define BT_   256       // B*T
#define BN_   512       // B*N

__device__ __forceinline__ float gelu_exact(float x) {
    return 0.5f * x * (1.0f + erff(x * 0.70710678118654752f));
}
__device__ __forceinline__ float bfbits2f(short s) {
    unsigned int u = ((unsigned int)(unsigned short)s) << 16;
    return __uint_as_float(u);
}
// load 32 consecutive bf16 from LDS (16B-aligned) as fp32
__device__ __forceinline__ void ld32lds(const bf16* p, float* o) {
    const short8* sp = (const short8*)p;
#pragma unroll
    for (int i = 0; i < 4; i++) {
        short8 s = sp[i];
#pragma unroll
        for (int j = 0; j < 8; j++) o[i * 8 + j] = bfbits2f(s[j]);
    }
}

// ---------------------------------------------------------------------------
// Repack weights into MFMA B-fragment layout + pack spatial qkv biases.
struct RepackDesc { const float* W; bf16* out; int K, N, ntt, ntoff, L, start; };
struct RepackArgs {
    RepackDesc d[9]; int total;
    const float *bq, *bk, *bv; float* spb;
};

__global__ void k_repack(RepackArgs ra) {
    int gid = blockIdx.x * blockDim.x + threadIdx.x;
    if (gid >= ra.total) {
        int i = gid - ra.total;
        if (i < 3 * 384) {
            int l = i / 384, c = i % 384;
            float v = (c < 128) ? ra.bq[l * 128 + c]
                    : (c < 256) ? ra.bk[l * 128 + c - 128]
                                : ra.bv[l * 128 + c - 256];
            ra.spb[i] = v;
        }
        return;
    }
    int fi = 0;
    while (fi < 8 && gid >= ra.d[fi + 1].start) fi++;
    RepackDesc dd = ra.d[fi];
    int r = gid - dd.start;
    int lane = r & 63; r >>= 6;
    int ntiles = dd.N >> 4;
    int nt = r % ntiles; r /= ntiles;
    int ktiles = dd.K >> 5;
    int kt = r % ktiles;
    int l = r / ktiles;
    int quad = lane >> 4, cc = lane & 15;
    const float* Wl = dd.W + (size_t)l * dd.K * dd.N;
    bf16* o = dd.out + ((((size_t)l * ktiles + kt) * dd.ntt + nt + dd.ntoff) * 64 + lane) * 8;
    int kb = kt * 32 + quad * 8;
    int n = nt * 16 + cc;
#pragma unroll
    for (int j = 0; j < 8; j++)
        o[j] = __float2bfloat16(Wl[(size_t)(kb + j) * dd.N + n]);
}

// ---------------------------------------------------------------------------
// FUSED 3-layer spatial stack. One block per (b,t) graph, 512 thr = 8 waves.
// Dedicated padded aggf -> 3 barriers/layer. qkv/Ws GEMMs software-pipelined
// (2-deep kt double-buffer, R14-proven mechanism).
__global__ __launch_bounds__(512, 1)
void k_spatial3(const float* __restrict__ inp, const float* __restrict__ projW,
                const float* __restrict__ projB,
                const short8* __restrict__ BpQKV, const short8* __restrict__ BpWS,
                const float* __restrict__ spb, const float* __restrict__ bs,
                const float* __restrict__ lng, const float* __restrict__ lnb,
                const float* __restrict__ ea, const float* __restrict__ Weg,
                const float* __restrict__ beg, const float* __restrict__ tpos,
                float* __restrict__ z32g) {
    __shared__ short smem[78208];            // 156416 B
    bf16* hb = (bf16*)smem;                  // [0,8704)s: 64 x 136
    bf16* qk = (bf16*)(smem + 8704);         // 64 x 264 (q|k)
    bf16* Vt = (bf16*)(smem + 25600);        // 128 x 72 (d-major)
    bf16* Ps = (bf16*)(smem + 34816);        // h*4608 + m*72
    float* aggf = (float*)(smem + 53248);    // 64 x 132 fp32 (dedicated)
    float* fsm = aggf;                       // proj staging overlay
    float* EAs = (float*)(smem + 70144);     // 4032 fp32

    int bt = blockIdx.x;
    int tid = threadIdx.x;
    int lane = tid & 63, w = tid >> 6;
    int quad = lane >> 4, col = lane & 15;
    int w4 = w & 3, wh = w >> 2;
    const float scale = 0.17677669529663687f;   // 1/sqrt(32)

    for (int i = tid; i < 896; i += 512)
        fsm[i] = (i < 768) ? projW[i] : projB[i - 768];
    {
        const float* eag = ea + (size_t)bt * E_;
        for (int i = tid; i < E_; i += 512) EAs[i] = eag[i];
    }
    __syncthreads();
    float hreg[32];
    if (w < 4) {
#pragma unroll
        for (int r = 0; r < 4; r++) {
            int n = w * 16 + quad * 4 + r;
            const float* xr = inp + (size_t)(bt * 64 + n) * F_;
            float xin[6];
#pragma unroll
            for (int k2 = 0; k2 < 6; k2++) xin[k2] = xr[k2];
#pragma unroll
            for (int tt = 0; tt < 8; tt++) {
                int c = tt * 16 + col;
                float a = fsm[768 + c];
#pragma unroll
                for (int k2 = 0; k2 < 6; k2++) a = fmaf(xin[k2], fsm[k2 * 128 + c], a);
                hreg[tt * 4 + r] = a;
                hb[n * 136 + c] = __float2bfloat16(a);
            }
        }
    }
    __syncthreads();                         // B0

    for (int l = 0; l < 3; l++) {
        // ---- phase 1: qkv GEMM (pipelined B loads) ----
        {
            floatx4 acc[12];
#pragma unroll
            for (int tt = 0; tt < 12; tt++) acc[tt] = (floatx4){0.f, 0.f, 0.f, 0.f};
            const short8* bpl = BpQKV + (size_t)l * 6144 + (size_t)(wh * 12) * 64 + lane;
            short8 bb[2][12];
#pragma unroll
            for (int tt = 0; tt < 12; tt++) bb[0][tt] = bpl[tt * 64];
#pragma unroll
            for (int kt = 0; kt < 4; kt++) {
                int cur = kt & 1;
                if (kt < 3) {
                    const short8* bpn = bpl + (size_t)((kt + 1) * 24) * 64;
#pragma unroll
                    for (int tt = 0; tt < 12; tt++) bb[cur ^ 1][tt] = bpn[tt * 64];
                }
                short8 a = *(const short8*)&hb[(w4 * 16 + col) * 136 + kt * 32 + quad * 8];
#pragma unroll
                for (int tt = 0; tt < 12; tt++)
                    acc[tt] = __builtin_amdgcn_mfma_f32_16x16x32_bf16(a, bb[cur][tt], acc[tt], 0, 0, 0);
            }
            const float* bias = spb + l * 384;
#pragma unroll
            for (int tt = 0; tt < 12; tt++) {
                int c = wh * 192 + tt * 16 + col;
                float bv = bias[c];
#pragma unroll
                for (int r = 0; r < 4; r++) {
                    int row = w4 * 16 + quad * 4 + r;
                    bf16 v = __float2bfloat16(acc[tt][r] + bv);
                    if (c < 256) qk[row * 264 + c] = v;
                    else         Vt[(c - 256) * 72 + row] = v;
                }
            }
        }
        __syncthreads();                     // B1: qk/Vt visible
        // ---- phase 2: attention (no barrier until aggf done) ----
        int h = w4, half = wh;
        int hoff = h * 32;
        const float* Wel = Weg + l * 128 + hoff;
        const float* bel = beg + l * 128 + hoff;
        float qWe;
        {
            int dst = half * 32 + (lane & 31);
            float qr[32];
            ld32lds(&qk[dst * 264 + hoff], qr);
            float s0 = 0.f, s1 = 0.f, s2 = 0.f, s3 = 0.f;
#pragma unroll
            for (int c2 = 0; c2 < 32; c2 += 4) {
                s0 = fmaf(qr[c2], Wel[c2], s0);
                s1 = fmaf(qr[c2 + 1], Wel[c2 + 1], s1);
                s2 = fmaf(qr[c2 + 2], Wel[c2 + 2], s2);
                s3 = fmaf(qr[c2 + 3], Wel[c2 + 3], s3);
            }
            qWe = (s0 + s1) + (s2 + s3);
        }
        float s[2][4][4], ev[2][4][4];
        {
            short8 aA[2], bB[4];
#pragma unroll
            for (int mtl = 0; mtl < 2; mtl++)
                aA[mtl] = *(const short8*)&qk[((half * 2 + mtl) * 16 + col) * 264 + hoff + quad * 8];
#pragma unroll
            for (int nt = 0; nt < 4; nt++)
                bB[nt] = *(const short8*)&qk[(nt * 16 + col) * 264 + 128 + hoff + quad * 8];
#pragma unroll
            for (int mtl = 0; mtl < 2; mtl++)
#pragma unroll
                for (int nt = 0; nt < 4; nt++) {
                    floatx4 acc = (floatx4){0.f, 0.f, 0.f, 0.f};
                    acc = __builtin_amdgcn_mfma_f32_16x16x32_bf16(aA[mtl], bB[nt], acc, 0, 0, 0);
#pragma unroll
                    for (int r = 0; r < 4; r++) s[mtl][nt][r] = acc[r];
                }
        }
        float ls[2][4], ae[2][4], inv[2][4];
#pragma unroll
        for (int mtl = 0; mtl < 2; mtl++)
#pragma unroll
            for (int r = 0; r < 4; r++) {
                int m = half * 32 + mtl * 16 + quad * 4 + r;
                float qWeR = __shfl(qWe, mtl * 16 + quad * 4 + r, 64);
                float rmax = -1e30f;
#pragma unroll
                for (int nt = 0; nt < 4; nt++) {
                    int n = nt * 16 + col;
                    bool diag = (m == n);
                    int eid = diag ? 0 : (n * 63 + m - (m > n ? 1 : 0));
                    float eav = diag ? 0.f : EAs[eid];
                    ev[mtl][nt][r] = eav;
                    float al = diag ? -1e30f
                                    : scale * (s[mtl][nt][r] + eav * qWeR);
                    s[mtl][nt][r] = al;
                    rmax = fmaxf(rmax, al);
                }
#pragma unroll
                for (int mk2 = 1; mk2 <= 8; mk2 <<= 1)
                    rmax = fmaxf(rmax, __shfl_xor(rmax, mk2, 64));
                float lsum = 0.f, aesum = 0.f;
#pragma unroll
                for (int nt = 0; nt < 4; nt++) {
                    float p = __expf(s[mtl][nt][r] - rmax);
                    s[mtl][nt][r] = p;
                    lsum += p;
                    aesum = fmaf(p, ev[mtl][nt][r], aesum);
                }
#pragma unroll
                for (int mk2 = 1; mk2 <= 8; mk2 <<= 1) {
                    lsum += __shfl_xor(lsum, mk2, 64);
                    aesum += __shfl_xor(aesum, mk2, 64);
                }
                ls[mtl][r] = lsum;
                ae[mtl][r] = aesum;
                inv[mtl][r] = 1.0f / lsum;
            }
        // PV: P hi/lo compensated bf16 split (Ps wave-private)
        bf16* PsH = Ps + h * 4608;
        floatx4 oacc[2][2];
#pragma unroll
        for (int mtl = 0; mtl < 2; mtl++)
#pragma unroll
            for (int ntB = 0; ntB < 2; ntB++) oacc[mtl][ntB] = (floatx4){0.f, 0.f, 0.f, 0.f};
#pragma unroll
        for (int p = 0; p < 2; p++) {
#pragma unroll
            for (int mtl = 0; mtl < 2; mtl++)
#pragma unroll
                for (int q2 = 0; q2 < 2; q2++) {
                    int nl = q2 * 16 + col;
                    int base0 = (half * 32 + mtl * 16 + quad * 4) * 72 + ((nl >> 3) * 2) * 8 + (nl & 7);
#pragma unroll
                    for (int r = 0; r < 4; r++) {
                        float p_ = s[mtl][2 * p + q2][r];
                        bf16 hi = __float2bfloat16(p_);
                        bf16 lo = __float2bfloat16(p_ - bfbits2f(*(short*)&hi));
                        PsH[base0 + r * 72] = hi;
                        PsH[base0 + r * 72 + 8] = lo;
                    }
                }
            short8 aPh[2], aPl[2], bV[2];
#pragma unroll
            for (int mtl = 0; mtl < 2; mtl++) {
                int rb = (half * 32 + mtl * 16 + col) * 72 + quad * 16;
                aPh[mtl] = *(const short8*)&PsH[rb];
                aPl[mtl] = *(const short8*)&PsH[rb + 8];
            }
#pragma unroll
            for (int ntB = 0; ntB < 2; ntB++)
                bV[ntB] = *(const short8*)&Vt[(hoff + ntB * 16 + col) * 72 + p * 32 + quad * 8];
#pragma unroll
            for (int mtl = 0; mtl < 2; mtl++)
#pragma unroll
                for (int ntB = 0; ntB < 2; ntB++) {
                    oacc[mtl][ntB] = __builtin_amdgcn_mfma_f32_16x16x32_bf16(aPh[mtl], bV[ntB], oacc[mtl][ntB], 0, 0, 0);
                    oacc[mtl][ntB] = __builtin_amdgcn_mfma_f32_16x16x32_bf16(aPl[mtl], bV[ntB], oacc[mtl][ntB], 0, 0, 0);
                }
        }
#pragma unroll
        for (int mtl = 0; mtl < 2; mtl++)
#pragma unroll
            for (int ntB = 0; ntB < 2; ntB++) {
                int c = hoff + ntB * 16 + col;
                float Wc = Wel[ntB * 16 + col];
                float bc = bel[ntB * 16 + col];
#pragma unroll
                for (int r = 0; r < 4; r++) {
                    int m = half * 32 + mtl * 16 + quad * 4 + r;
                    aggf[m * 132 + c] = fmaf(fmaf(ae[mtl][r], Wc, oacc[mtl][ntB][r]),
                                             inv[mtl][r], bc);
                }
            }
        __syncthreads();                     // B2: agg visible (qk reads also done)
        // ---- epilogue: Ws GEMM + agg + residual + LN (waves 0-3, pipelined) ----
        if (w < 4) {
            floatx4 acc2[8];
#pragma unroll
            for (int tt = 0; tt < 8; tt++) acc2[tt] = (floatx4){0.f, 0.f, 0.f, 0.f};
            const short8* bpl = BpWS + (size_t)l * 2048 + lane;
            short8 bb[2][8];
#pragma unroll
            for (int tt = 0; tt < 8; tt++) bb[0][tt] = bpl[tt * 64];
#pragma unroll
            for (int kt = 0; kt < 4; kt++) {
                int cur = kt & 1;
                if (kt < 3) {
                    const short8* bpn = bpl + (size_t)((kt + 1) * 8) * 64;
#pragma unroll
                    for (int tt = 0; tt < 8; tt++) bb[cur ^ 1][tt] = bpn[tt * 64];
                }
                short8 a = *(const short8*)&hb[(w * 16 + col) * 136 + kt * 32 + quad * 8];
#pragma unroll
                for (int tt = 0; tt < 8; tt++)
                    acc2[tt] = __builtin_amdgcn_mfma_f32_16x16x32_bf16(a, bb[cur][tt], acc2[tt], 0, 0, 0);
            }
            const float* bsl = bs + l * 128;
            float vv[32], rs[4] = {0.f, 0.f, 0.f, 0.f};
#pragma unroll
            for (int tt = 0; tt < 8; tt++) {
                int c = tt * 16 + col;
                float bv = bsl[c];
#pragma unroll
                for (int r = 0; r < 4; r++) {
                    int row = w * 16 + quad * 4 + r;
                    float v = acc2[tt][r] + bv + aggf[row * 132 + c] + hreg[tt * 4 + r];
                    vv[tt * 4 + r] = v;
                    rs[r] += v;
                }
            }
#pragma unroll
            for (int m = 1; m <= 8; m <<= 1)
#pragma unroll
                for (int r = 0; r < 4; r++) rs[r] += __shfl_xor(rs[r], m, 64);
            float mean[4], vs[4] = {0.f, 0.f, 0.f, 0.f};
#pragma unroll
            for (int r = 0; r < 4; r++) mean[r] = rs[r] * (1.0f / 128.0f);
#pragma unroll
            for (int i = 0; i < 32; i++) {
                float d = vv[i] - mean[i & 3];
                vv[i] = d;
                vs[i & 3] += d * d;
            }
#pragma unroll
            for (int m = 1; m <= 8; m <<= 1)
#pragma unroll
                for (int r = 0; r < 4; r++) vs[r] += __shfl_xor(vs[r], m, 64);
            float inv2[4];
#pragma unroll
            for (int r = 0; r < 4; r++) inv2[r] = rsqrtf(vs[r] * (1.0f / 128.0f) + 1e-5f);
            const float* gl = lng + l * 128;
            const float* bl = lnb + l * 128;
            if (l < 2) {
#pragma unroll
                for (int tt = 0; tt < 8; tt++) {
                    int c = tt * 16 + col;
                    float gc = gl[c], bc = bl[c];
#pragma unroll
                    for (int r = 0; r < 4; r++) {
                        float y = vv[tt * 4 + r] * inv2[r] * gc + bc;
                        int n = w * 16 + quad * 4 + r;
                        hreg[tt * 4 + r] = y;
                        hb[n * 136 + c] = __float2bfloat16(y);
                    }
                }
            } else {
                int b = bt >> 5, t_ = bt & 31;
#pragma unroll
                for (int tt = 0; tt < 8; tt++) {
                    int c = tt * 16 + col;
                    float gc = gl[c], bc = bl[c], pc = tpos[t_ * 128 + c];
#pragma unroll
                    for (int r = 0; r < 4; r++) {
                        float y = vv[tt * 4 + r] * inv2[r] * gc + bc;
                        int n = w * 16 + quad * 4 + r;
                        z32g[((size_t)(b * 64 + n) * 32 + t_) * 128 + c] = y + pc;
                    }
                }
            }
        }
        __syncthreads();                     // B3: layer complete
    }
}

// ---------------------------------------------------------------------------
// FUSED 3-layer temporal stack (R14 proven, 82.7 us). Software-pipelined
// B-fragment loads in qkv/Wo/W1/W2 phases.
__global__ __launch_bounds__(512, 4)
void k_temporal3(const float* __restrict__ z32g,
                 const short8* __restrict__ BpQKV, const short8* __restrict__ BpWO,
                 const short8* __restrict__ BpW1, const short8* __restrict__ BpW2,
                 const float* __restrict__ bqkv, const float* __restrict__ bo,
                 const float* __restrict__ ln1g, const float* __restrict__ ln1b,
                 const float* __restrict__ b1, const float* __restrict__ b2,
                 const float* __restrict__ ln2g, const float* __restrict__ ln2b,
                 bf16* __restrict__ zlastb) {
    __shared__ short smem[32000];            // 64000 B
    bf16* zb  = (bf16*)smem;                 // [0,4352)s: 32 x 136
    bf16* qk  = (bf16*)(smem + 4352);        // 32 x 264
    bf16* Ps  = (bf16*)(smem + 12800);       // (h*2+mh)*1152
    bf16* Vt  = (bf16*)(smem + 22016);       // d*40 + t
    bf16* o16 = (bf16*)(smem + 27136);       // 32 x 136
    float* lnp = (float*)(smem + 31488);     // 4x32x2 fp32
    bf16* f1  = (bf16*)(smem + 4352);        // overlay: 32 x 520

    int bn = blockIdx.x;
    int tid = threadIdx.x;
    int lane = tid & 63, w = tid >> 6;
    int quad = lane >> 4, col = lane & 15;
    int mt = w & 1, cq = w >> 1;
    const float scale = 0.17677669529663687f;

    for (int i = tid; i < 4096; i += 512) {
        float v = z32g[(size_t)bn * 4096 + i];
        zb[(i >> 7) * 136 + (i & 127)] = __float2bfloat16(v);
    }
    float zreg[8];
#pragma unroll
    for (int t2 = 0; t2 < 2; t2++)
#pragma unroll
        for (int r = 0; r < 4; r++)
            zreg[t2 * 4 + r] = z32g[(size_t)bn * 4096 +
                                    (mt * 16 + quad * 4 + r) * 128 + cq * 32 + t2 * 16 + col];
    __syncthreads();

    for (int l = 0; l < 3; l++) {
        // ---- phase 1: qkv GEMM (pipelined B loads) ----
        {
            floatx4 acc[6];
#pragma unroll
            for (int tt = 0; tt < 6; tt++) acc[tt] = (floatx4){0.f, 0.f, 0.f, 0.f};
            const short8* bpl = BpQKV + (size_t)l * 6144 + (size_t)(cq * 6) * 64 + lane;
            short8 bb[2][6];
#pragma unroll
            for (int tt = 0; tt < 6; tt++) bb[0][tt] = bpl[tt * 64];
#pragma unroll
            for (int kt = 0; kt < 4; kt++) {
                int cur = kt & 1;
                if (kt < 3) {
                    const short8* bpn = bpl + (size_t)((kt + 1) * 24) * 64;
#pragma unroll
                    for (int tt = 0; tt < 6; tt++) bb[cur ^ 1][tt] = bpn[tt * 64];
                }
                short8 a = *(const short8*)&zb[(mt * 16 + col) * 136 + kt * 32 + quad * 8];
#pragma unroll
                for (int tt = 0; tt < 6; tt++)
                    acc[tt] = __builtin_amdgcn_mfma_f32_16x16x32_bf16(a, bb[cur][tt], acc[tt], 0, 0, 0);
            }
            const float* bias = bqkv + l * 384;
#pragma unroll
            for (int tt = 0; tt < 6; tt++) {
                int c = cq * 96 + tt * 16 + col;
                float bv = bias[c];
#pragma unroll
                for (int r = 0; r < 4; r++) {
                    int row = mt * 16 + quad * 4 + r;
                    bf16 v = __float2bfloat16(acc[tt][r] + bv);
                    if (c < 256) qk[row * 264 + c] = v;
                    else         Vt[(c - 256) * 40 + row] = v;
                }
            }
        }
        __syncthreads();                     // B1
        // ---- phase 2: attention. wave=(h=w&3, mh=w>>2) ----
        {
            int h = w & 3, mh = w >> 2;
            int hoff = h * 32;
            bf16* PsH = Ps + (h * 2 + mh) * 1152;
            float s[2][4];
            short8 aA = *(const short8*)&qk[(mh * 16 + col) * 264 + hoff + quad * 8];
            short8 bB[2];
#pragma unroll
            for (int nt = 0; nt < 2; nt++)
                bB[nt] = *(const short8*)&qk[(nt * 16 + col) * 264 + 128 + hoff + quad * 8];
#pragma unroll
            for (int nt = 0; nt < 2; nt++) {
                floatx4 acc = (floatx4){0.f, 0.f, 0.f, 0.f};
                acc = __builtin_amdgcn_mfma_f32_16x16x32_bf16(aA, bB[nt], acc, 0, 0, 0);
#pragma unroll
                for (int r = 0; r < 4; r++) s[nt][r] = acc[r];
            }
            float inv[4];
#pragma unroll
            for (int r = 0; r < 4; r++) {
                int m = mh * 16 + quad * 4 + r;
                float rmax = -1e30f;
#pragma unroll
                for (int nt = 0; nt < 2; nt++) {
                    int n = nt * 16 + col;
                    float al = (n > m) ? -1e30f : s[nt][r] * scale;
                    s[nt][r] = al;
                    rmax = fmaxf(rmax, al);
                }
#pragma unroll
                for (int mk2 = 1; mk2 <= 8; mk2 <<= 1)
                    rmax = fmaxf(rmax, __shfl_xor(rmax, mk2, 64));
                float lsum = 0.f;
#pragma unroll
                for (int nt = 0; nt < 2; nt++) {
                    float p = __expf(s[nt][r] - rmax);
                    s[nt][r] = p;
                    lsum += p;
                }
#pragma unroll
                for (int mk2 = 1; mk2 <= 8; mk2 <<= 1)
                    lsum += __shfl_xor(lsum, mk2, 64);
                inv[r] = 1.0f / lsum;
            }
#pragma unroll
            for (int nt = 0; nt < 2; nt++) {
                int n = nt * 16 + col;
                int base0 = (quad * 4) * 72 + ((n >> 3) * 2) * 8 + (n & 7);
#pragma unroll
                for (int r = 0; r < 4; r++) {
                    float p_ = s[nt][r];
                    bf16 hi = __float2bfloat16(p_);
                    bf16 lo = __float2bfloat16(p_ - bfbits2f(*(short*)&hi));
                    PsH[base0 + r * 72] = hi;
                    PsH[base0 + r * 72 + 8] = lo;
                }
            }
            floatx4 oacc[2];
#pragma unroll
            for (int nt = 0; nt < 2; nt++) oacc[nt] = (floatx4){0.f, 0.f, 0.f, 0.f};
            short8 aPh = *(const short8*)&PsH[col * 72 + quad * 16];
            short8 aPl = *(const short8*)&PsH[col * 72 + quad * 16 + 8];
            short8 bV[2];
#pragma unroll
            for (int nt = 0; nt < 2; nt++)
                bV[nt] = *(const short8*)&Vt[(hoff + nt * 16 + col) * 40 + quad * 8];
#pragma unroll
            for (int nt = 0; nt < 2; nt++) {
                oacc[nt] = __builtin_amdgcn_mfma_f32_16x16x32_bf16(aPh, bV[nt], oacc[nt], 0, 0, 0);
                oacc[nt] = __builtin_amdgcn_mfma_f32_16x16x32_bf16(aPl, bV[nt], oacc[nt], 0, 0, 0);
            }
#pragma unroll
            for (int nt = 0; nt < 2; nt++) {
                int c = hoff + nt * 16 + col;
#pragma unroll
                for (int r = 0; r < 4; r++)
                    o16[(mh * 16 + quad * 4 + r) * 136 + c] =
                        __float2bfloat16(oacc[nt][r] * inv[r]);
            }
        }
        __syncthreads();                     // B2
        // ---- Wo GEMM + residual + LN1 (pipelined B loads) ----
        {
            floatx4 acc2[2];
#pragma unroll
            for (int tt = 0; tt < 2; tt++) acc2[tt] = (floatx4){0.f, 0.f, 0.f, 0.f};
            const short8* bpl = BpWO + (size_t)l * 2048 + (size_t)(cq * 2) * 64 + lane;
            short8 bb[2][2];
#pragma unroll
            for (int tt = 0; tt < 2; tt++) bb[0][tt] = bpl[tt * 64];
#pragma unroll
            for (int kt = 0; kt < 4; kt++) {
                int cur = kt & 1;
                if (kt < 3) {
                    const short8* bpn = bpl + (size_t)((kt + 1) * 8) * 64;
#pragma unroll
                    for (int tt = 0; tt < 2; tt++) bb[cur ^ 1][tt] = bpn[tt * 64];
                }
                short8 a = *(const short8*)&o16[(mt * 16 + col) * 136 + kt * 32 + quad * 8];
#pragma unroll
                for (int tt = 0; tt < 2; tt++)
                    acc2[tt] = __builtin_amdgcn_mfma_f32_16x16x32_bf16(a, bb[cur][tt], acc2[tt], 0, 0, 0);
            }
            const float* bol = bo + l * 128;
            float vv[8], rs[4] = {0.f, 0.f, 0.f, 0.f}, rq[4] = {0.f, 0.f, 0.f, 0.f};
#pragma unroll
            for (int tt = 0; tt < 2; tt++) {
                int c = cq * 32 + tt * 16 + col;
                float bv = bol[c];
#pragma unroll
                for (int r = 0; r < 4; r++) {
                    float v = acc2[tt][r] + bv + zreg[tt * 4 + r];
                    vv[tt * 4 + r] = v;
                    rs[r] += v;
                    rq[r] = fmaf(v, v, rq[r]);
                }
            }
#pragma unroll
            for (int m = 1; m <= 8; m <<= 1)
#pragma unroll
                for (int r = 0; r < 4; r++) {
                    rs[r] += __shfl_xor(rs[r], m, 64);
                    rq[r] += __shfl_xor(rq[r], m, 64);
                }
            if (col == 0) {
#pragma unroll
                for (int r = 0; r < 4; r++) {
                    int row = mt * 16 + quad * 4 + r;
                    lnp[(cq * 32 + row) * 2] = rs[r];
                    lnp[(cq * 32 + row) * 2 + 1] = rq[r];
                }
            }
            __syncthreads();                 // B3
            const float* gl = ln1g + l * 128;
            const float* bl = ln1b + l * 128;
#pragma unroll
            for (int r = 0; r < 4; r++) {
                int row = mt * 16 + quad * 4 + r;
                float sm = 0.f, sq = 0.f;
#pragma unroll
                for (int q2 = 0; q2 < 4; q2++) {
                    sm += lnp[(q2 * 32 + row) * 2];
                    sq += lnp[(q2 * 32 + row) * 2 + 1];
                }
                float mean = sm * (1.0f / 128.0f);
                float var = sq * (1.0f / 128.0f) - mean * mean;
                float iv = rsqrtf(var + 1e-5f);
#pragma unroll
                for (int tt = 0; tt < 2; tt++) {
                    int c = cq * 32 + tt * 16 + col;
                    float y = (vv[tt * 4 + r] - mean) * iv * gl[c] + bl[c];
                    zreg[tt * 4 + r] = y;
                    zb[row * 136 + c] = __float2bfloat16(y);
                }
            }
        }
        __syncthreads();                     // B4
        // ---- W1 GEMM + gelu (pipelined B loads) ----
        {
            floatx4 acc3[8];
#pragma unroll
            for (int tt = 0; tt < 8; tt++) acc3[tt] = (floatx4){0.f, 0.f, 0.f, 0.f};
            const short8* bpl = BpW1 + (size_t)l * 8192 + (size_t)(cq * 8) * 64 + lane;
            short8 bb[2][8];
#pragma unroll
            for (int tt = 0; tt < 8; tt++) bb[0][tt] = bpl[tt * 64];
#pragma unroll
            for (int kt = 0; kt < 4; kt++) {
                int cur = kt & 1;
                if (kt < 3) {
                    const short8* bpn = bpl + (size_t)((kt + 1) * 32) * 64;
#pragma unroll
                    for (int tt = 0; tt < 8; tt++) bb[cur ^ 1][tt] = bpn[tt * 64];
                }
                short8 a = *(const short8*)&zb[(mt * 16 + col) * 136 + kt * 32 + quad * 8];
#pragma unroll
                for (int tt = 0; tt < 8; tt++)
                    acc3[tt] = __builtin_amdgcn_mfma_f32_16x16x32_bf16(a, bb[cur][tt], acc3[tt], 0, 0, 0);
            }
            const float* b1l = b1 + l * 512;
#pragma unroll
            for (int tt = 0; tt < 8; tt++) {
                int c = cq * 128 + tt * 16 + col;
                float bv = b1l[c];
#pragma unroll
                for (int r = 0; r < 4; r++) {
                    float v = gelu_exact(acc3[tt][r] + bv);
                    f1[(mt * 16 + quad * 4 + r) * 520 + c] = __float2bfloat16(v);
                }
            }
        }
        __syncthreads();                     // B5
        // ---- W2 GEMM + residual + LN2 (pipelined B loads, K=512) ----
        {
            floatx4 acc4[2];
#pragma unroll
            for (int tt = 0; tt < 2; tt++) acc4[tt] = (floatx4){0.f, 0.f, 0.f, 0.f};
            const short8* bpl = BpW2 + (size_t)l * 8192 + (size_t)(cq * 2) * 64 + lane;
            short8 bb[2][2];
#pragma unroll
            for (int tt = 0; tt < 2; tt++) bb[0][tt] = bpl[tt * 64];
#pragma unroll
            for (int kt = 0; kt < 16; kt++) {
                int cur = kt & 1;
                if (kt < 15) {
                    const short8* bpn = bpl + (size_t)((kt + 1) * 8) * 64;
#pragma unroll
                    for (int tt = 0; tt < 2; tt++) bb[cur ^ 1][tt] = bpn[tt * 64];
                }
                short8 a = *(const short8*)&f1[(mt * 16 + col) * 520 + kt * 32 + quad * 8];
#pragma unroll
                for (int tt = 0; tt < 2; tt++)
                    acc4[tt] = __builtin_amdgcn_mfma_f32_16x16x32_bf16(a, bb[cur][tt], acc4[tt], 0, 0, 0);
            }
            const float* b2l = b2 + l * 128;
            float vv[8], rs[4] = {0.f, 0.f, 0.f, 0.f}, rq[4] = {0.f, 0.f, 0.f, 0.f};
#pragma unroll
            for (int tt = 0; tt < 2; tt++) {
                int c = cq * 32 + tt * 16 + col;
                float bv = b2l[c];
#pragma unroll
                for (int r = 0; r < 4; r++) {
                    float v = acc4[tt][r] + bv + zreg[tt * 4 + r];
                    vv[tt * 4 + r] = v;
                    rs[r] += v;
                    rq[r] = fmaf(v, v, rq[r]);
                }
            }
#pragma unroll
            for (int m = 1; m <= 8; m <<= 1)
#pragma unroll
                for (int r = 0; r < 4; r++) {
                    rs[r] += __shfl_xor(rs[r], m, 64);
                    rq[r] += __shfl_xor(rq[r], m, 64);
                }
            if (col == 0) {
#pragma unroll
                for (int r = 0; r < 4; r++) {
                    int row = mt * 16 + quad * 4 + r;
                    lnp[(cq * 32 + row) * 2] = rs[r];
                    lnp[(cq * 32 + row) * 2 + 1] = rq[r];
                }
            }
            __syncthreads();                 // B6
            const float* gl = ln2g + l * 128;
            const float* bl = ln2b + l * 128;
#pragma unroll
            for (int r = 0; r < 4; r++) {
                int row = mt * 16 + quad * 4 + r;
                float sm = 0.f, sq = 0.f;
#pragma unroll
                for (int q2 = 0; q2 < 4; q2++) {
                    sm += lnp[(q2 * 32 + row) * 2];
                    sq += lnp[(q2 * 32 + row) * 2 + 1];
                }
                float mean = sm * (1.0f / 128.0f);
                float var = sq * (1.0f / 128.0f) - mean * mean;
                float iv = rsqrtf(var + 1e-5f);
#pragma unroll
                for (int tt = 0; tt < 2; tt++) {
                    int c = cq * 32 + tt * 16 + col;
                    float y = (vv[tt * 4 + r] - mean) * iv * gl[c] + bl[c];
                    zreg[tt * 4 + r] = y;
                    if (l < 2) zb[row * 136 + c] = __float2bfloat16(y);
                    else if (row == 31) zlastb[(size_t)bn * 128 + c] = __float2bfloat16(y);
                }
            }
        }
        __syncthreads();                     // B7
    }
}

// ---------------------------------------------------------------------------
// Head (MFMA): out = gelu(zlast @ W1 + b1) @ W2 + b2. Grid 32 x 256 thr.
__global__ __launch_bounds__(256)
void k_head(const bf16* __restrict__ zlastb, const short8* __restrict__ BpHW1,
            const float* __restrict__ b1, const float* __restrict__ W2,
            const float* __restrict__ b2, float* __restrict__ out) {
    __shared__ bf16 h1[16 * 136];
    int blk = blockIdx.x;
    int tid = threadIdx.x;
    int lane = tid & 63, w = tid >> 6;
    int quad = lane >> 4, col = lane & 15;
    {
        floatx4 acc[2];
        acc[0] = (floatx4){0.f, 0.f, 0.f, 0.f};
        acc[1] = (floatx4){0.f, 0.f, 0.f, 0.f};
        const short8* Ap = (const short8*)(zlastb + (size_t)(blk * 16 + col) * 128) + quad;
        for (int kt = 0; kt < 4; kt++) {
            short8 a = Ap[kt * 4];
            const short8* bp = BpHW1 + (size_t)(kt * 8 + w * 2) * 64 + lane;
            acc[0] = __builtin_amdgcn_mfma_f32_16x16x32_bf16(a, bp[0], acc[0], 0, 0, 0);
            acc[1] = __builtin_amdgcn_mfma_f32_16x16x32_bf16(a, bp[64], acc[1], 0, 0, 0);
        }
#pragma unroll
        for (int tt = 0; tt < 2; tt++) {
            int c = w * 32 + tt * 16 + col;
            float bv = b1[c];
#pragma unroll
            for (int r = 0; r < 4; r++)
                h1[(quad * 4 + r) * 136 + c] = __float2bfloat16(gelu_exact(acc[tt][r] + bv));
        }
    }
    __syncthreads();
    if (tid < 96) {
        int row = tid / 6, c = tid % 6;
        float a0 = 0.f, a1 = 0.f, a2 = 0.f, a3 = 0.f;
        const bf16* hr = &h1[row * 136];
#pragma unroll 8
        for (int k = 0; k < 128; k += 4) {
            a0 = fmaf(bfbits2f(*(const short*)&hr[k]),     W2[k * 6 + c], a0);
            a1 = fmaf(bfbits2f(*(const short*)&hr[k + 1]), W2[(k + 1) * 6 + c], a1);
            a2 = fmaf(bfbits2f(*(const short*)&hr[k + 2]), W2[(k + 2) * 6 + c], a2);
            a3 = fmaf(bfbits2f(*(const short*)&hr[k + 3]), W2[(k + 3) * 6 + c], a3);
        }
        out[(size_t)(blk * 16 + row) * 6 + c] = (a0 + a1) + (a2 + a3) + b2[c];
    }
}

// ---------------------------------------------------------------------------
extern "C" void kernel_launch(void* const* d_in, const int* in_sizes, int n_in,
                              void* d_out, int out_size, void* d_ws, size_t ws_size,
                              hipStream_t stream) {
    const float* input_frames = (const float*)d_in[0];
    const float* edge_attr    = (const float*)d_in[1];
    const float* proj_W  = (const float*)d_in[2];
    const float* proj_b  = (const float*)d_in[3];
    const float* sp_Wq   = (const float*)d_in[4];
    const float* sp_bq   = (const float*)d_in[5];
    const float* sp_Wk   = (const float*)d_in[6];
    const float* sp_bk   = (const float*)d_in[7];
    const float* sp_Wv   = (const float*)d_in[8];
    const float* sp_bv   = (const float*)d_in[9];
    const float* sp_We   = (const float*)d_in[10];
    const float* sp_be   = (const float*)d_in[11];
    const float* sp_Ws   = (const float*)d_in[12];
    const float* sp_bs   = (const float*)d_in[13];
    const float* sp_lng  = (const float*)d_in[14];
    const float* sp_lnb  = (const float*)d_in[15];
    const float* tpos    = (const float*)d_in[16];
    const float* t_Wqkv  = (const float*)d_in[17];
    const float* t_bqkv  = (const float*)d_in[18];
    const float* t_Wo    = (const float*)d_in[19];
    const float* t_bo    = (const float*)d_in[20];
    const float* t_ln1g  = (const float*)d_in[21];
    const float* t_ln1b  = (const float*)d_in[22];
    const float* t_W1    = (const float*)d_in[23];
    const float* t_b1    = (const float*)d_in[24];
    const float* t_W2    = (const float*)d_in[25];
    const float* t_b2    = (const float*)d_in[26];
    const float* t_ln2g  = (const float*)d_in[27];
    const float* t_ln2b  = (const float*)d_in[28];
    const float* head_W1 = (const float*)d_in[29];
    const float* head_b1 = (const float*)d_in[30];
    const float* head_W2 = (const float*)d_in[31];
    const float* head_b2 = (const float*)d_in[32];

    float* f     = (float*)d_ws;
    float* z32g  = f;                                  // 2M floats
    bf16*  zlastb = (bf16*)(f + (1u << 21));           // 64K bf16
    float* spb   = f + (1u << 21) + 65536;             // 1152 floats
    bf16* BpBase = (bf16*)(f + (1u << 21) + 65536 + 2048);
    bf16* BpSPQKV = BpBase;                            // 147456 bf16
    bf16* BpWS    = BpSPQKV + 147456;                  //  49152
    bf16* BpTQKV  = BpWS + 49152;                      // 147456
    bf16* BpWO    = BpTQKV + 147456;                   //  49152
    bf16* BpW1    = BpWO + 49152;                      // 196608
    bf16* BpW2    = BpW1 + 196608;                     // 196608
    bf16* BpHW1   = BpW2 + 196608;                     //  16384

    RepackArgs ra;
    int s = 0;
    auto mk = [&](int i, const float* W, bf16* out, int K, int N, int ntt, int ntoff, int L) {
        ra.d[i] = {W, out, K, N, ntt, ntoff, L, s};
        s += L * (K >> 5) * (N >> 4) * 64;
    };
    mk(0, sp_Wq, BpSPQKV, 128, 128, 24, 0, 3);
    mk(1, sp_Wk, BpSPQKV, 128, 128, 24, 8, 3);
    mk(2, sp_Wv, BpSPQKV, 128, 128, 24, 16, 3);
    mk(3, sp_Ws, BpWS, 128, 128, 8, 0, 3);
    mk(4, t_Wqkv, BpTQKV, 128, 384, 24, 0, 3);
    mk(5, t_Wo, BpWO, 128, 128, 8, 0, 3);
    mk(6, t_W1, BpW1, 128, 512, 32, 0, 3);
    mk(7, t_W2, BpW2, 512, 128, 8, 0, 3);
    mk(8, head_W1, BpHW1, 128, 128, 8, 0, 1);
    ra.total = s;
    ra.bq = sp_bq; ra.bk = sp_bk; ra.bv = sp_bv; ra.spb = spb;
    k_repack<<<(s + 1152 + 255) / 256, 256, 0, stream>>>(ra);

    k_spatial3<<<BT_, 512, 0, stream>>>(
        input_frames, proj_W, proj_b,
        (const short8*)BpSPQKV, (const short8*)BpWS,
        spb, sp_bs, sp_lng, sp_lnb, edge_attr, sp_We, sp_be, tpos, z32g);

    k_temporal3<<<BN_, 512, 0, stream>>>(
        z32g, (const short8*)BpTQKV, (const short8*)BpWO,
        (const short8*)BpW1, (const short8*)BpW2,
        t_bqkv, t_bo, t_ln1g, t_ln1b, t_b1, t_b2, t_ln2g, t_ln2b, zlastb);

    k_head<<<32, 256, 0, stream>>>(zlastb, (const short8*)BpHW1, head_b1,
                                   head_W2, head_b2, (float*)d_out);
}